// Round 11
// baseline (394.991 us; speedup 1.0000x reference)
//
#include <hip/hip_runtime.h>
#include <hip/hip_bf16.h>
#include <math.h>

#define T_STEPS 5
#define NNODES  10000
#define NM      (T_STEPS * NNODES)   // 50000 node-instances (t,n)
#define F_IN    16
#define NEDGES  160000
#define ETOT    (NEDGES + NNODES)    // + self loops
#define GW      8                    // waves per block in gruhead (512 threads)
#define GNPW    5                    // nodes per wave: 8*5=40 nodes/block, 250 blocks

// SGPR broadcast: readlane (uniform index)
#define RL(v, k)  __int_as_float(__builtin_amdgcn_readlane(__float_as_int(v), (k)))
#define RLI(v, k) __builtin_amdgcn_readlane((v), (k))

// ---------------- CSR build ----------------
__global__ __launch_bounds__(256) void k_count(const int* __restrict__ ei, int* __restrict__ counts) {
    int idx = blockIdx.x * 256 + threadIdx.x;
    if (idx >= ETOT) return;
    int dst = (idx < NEDGES) ? ei[NEDGES + idx] : (idx - NEDGES);
    atomicAdd(&counts[dst], 1);
}

__global__ __launch_bounds__(1024) void k_scan(const int* __restrict__ counts, int* __restrict__ offs) {
    __shared__ int ssum[1024];
    int t = threadIdx.x;
    const int chunk = (NNODES + 1023) / 1024;
    int start = t * chunk, end = min(start + chunk, NNODES);
    int s = 0;
    for (int i = start; i < end; i++) s += counts[i];
    ssum[t] = s;
    __syncthreads();
    for (int off = 1; off < 1024; off <<= 1) {
        int v = (t >= off) ? ssum[t - off] : 0;
        __syncthreads();
        ssum[t] += v;
        __syncthreads();
    }
    int excl = (t == 0) ? 0 : ssum[t - 1];
    for (int i = start; i < end; i++) { offs[i] = excl; excl += counts[i]; }
    if (t == 1023) offs[NNODES] = ssum[1023];
}

__global__ __launch_bounds__(256) void k_fill(const int* __restrict__ ei, const int* __restrict__ offs,
                                              int* __restrict__ cursor, int* __restrict__ csr) {
    int idx = blockIdx.x * 256 + threadIdx.x;
    if (idx >= ETOT) return;
    int src, dst;
    if (idx < NEDGES) { src = ei[idx]; dst = ei[NEDGES + idx]; }
    else              { src = dst = idx - NEDGES; }
    int p = atomicAdd(&cursor[dst], 1);
    csr[offs[dst] + p] = src;
}

// ---------------- one-time weight transpose: flat k-major + packed blob for persistent kernel ----------------
// blob layout (131072 B): h0rz float2[4096] @0 | h0n float[4096] @32768 | i1rz @49152 | i1n @81920 | h1rz @98304
// h1n float[4096] lives in its own global buffer (read per-k from L1 in the persistent kernel).
__global__ __launch_bounds__(256) void k_transpose(const float* __restrict__ Wi0, const float* __restrict__ Wh0,
                                                   const float* __restrict__ Wi1, const float* __restrict__ Wh1,
                                                   float* __restrict__ WiT0, float* __restrict__ WhT0,
                                                   float* __restrict__ WiT1, float* __restrict__ WhT1,
                                                   float2* __restrict__ h0rz, float* __restrict__ h0n,
                                                   float2* __restrict__ i1rz, float* __restrict__ i1n,
                                                   float2* __restrict__ h1rz, float* __restrict__ h1n) {
    int idx = blockIdx.x * 256 + threadIdx.x;
    if (idx < 6144)  { int k = idx / 192, r = idx % 192; WiT0[idx] = Wi0[r * 32 + k]; return; }
    idx -= 6144;
    if (idx < 12288) { int k = idx / 192, r = idx % 192; WhT0[idx] = Wh0[r * 64 + k]; return; }
    idx -= 12288;
    if (idx < 12288) { int k = idx / 192, r = idx % 192; WiT1[idx] = Wi1[r * 64 + k]; return; }
    idx -= 12288;
    if (idx < 12288) { int k = idx / 192, r = idx % 192; WhT1[idx] = Wh1[r * 64 + k]; return; }
    idx -= 12288;
    if (idx < 4096) { int k = idx >> 6, c = idx & 63;
                      h0rz[idx] = make_float2(Wh0[c * 64 + k], Wh0[(64 + c) * 64 + k]);
                      h0n[idx]  = Wh0[(128 + c) * 64 + k]; return; }
    idx -= 4096;
    if (idx < 4096) { int k = idx >> 6, c = idx & 63;
                      i1rz[idx] = make_float2(Wi1[c * 64 + k], Wi1[(64 + c) * 64 + k]);
                      i1n[idx]  = Wi1[(128 + c) * 64 + k]; return; }
    idx -= 4096;
    if (idx < 4096) { int k = idx >> 6, c = idx & 63;
                      h1rz[idx] = make_float2(Wh1[c * 64 + k], Wh1[(64 + c) * 64 + k]);
                      h1n[idx]  = Wh1[(128 + c) * 64 + k]; }
}

// ---------------- GAT0 projections for ALL timesteps ----------------
__global__ __launch_bounds__(256) void k_mm0_all(const float* __restrict__ x,      // [5N,16]
                                                 const float* __restrict__ W,     // [16,64]
                                                 const float* __restrict__ Wres,  // [16,64]
                                                 const float* __restrict__ asrc,  // [64]
                                                 const float* __restrict__ adst,  // [64]
                                                 float* __restrict__ xw, float* __restrict__ xres,
                                                 float* __restrict__ als, float* __restrict__ ald) {
    int wave = threadIdx.x >> 6, lane = threadIdx.x & 63;
    int m = blockIdx.x * 4 + wave;
    if (m >= NM) return;
    const float* xr = x + (size_t)m * F_IN;
    float xreg[F_IN];
#pragma unroll
    for (int k = 0; k < F_IN; k++) xreg[k] = xr[k];
    float acc = 0.f, accr = 0.f;
#pragma unroll
    for (int k = 0; k < F_IN; k++) {
        acc  += xreg[k] * W[k * 64 + lane];
        accr += xreg[k] * Wres[k * 64 + lane];
    }
    xw[(size_t)m * 64 + lane]   = acc;
    xres[(size_t)m * 64 + lane] = accr;
    float ps = acc * asrc[lane], pd = acc * adst[lane];
    for (int off = 16; off; off >>= 1) {
        ps += __shfl_down(ps, off, 32);
        pd += __shfl_down(pd, off, 32);
    }
    if ((lane & 31) == 0) {
        int h = lane >> 5;
        als[m * 2 + h] = ps;
        ald[m * 2 + h] = pd;
    }
}

// ---------------- fused GAT0 gather + ELU + residual + GAT1 projection, ALL timesteps ----------------
__global__ __launch_bounds__(256) void k_gat0_all(const float* __restrict__ xw,   // [5N,64]
                                                  const float* __restrict__ xres, // [5N,64]
                                                  const float* __restrict__ als,  // [5N,2]
                                                  const float* __restrict__ ald,  // [5N,2]
                                                  const int* __restrict__ offs, const int* __restrict__ csr,
                                                  const float* __restrict__ b,    // [64]
                                                  const float* __restrict__ W1,   // [64,32]
                                                  const float* __restrict__ Wres1,// [64,32]
                                                  const float* __restrict__ as1,  // [32]
                                                  const float* __restrict__ ad1v, // [32]
                                                  float* __restrict__ xw1, float* __restrict__ xres1,
                                                  float* __restrict__ als1, float* __restrict__ ald1) {
    int wave = threadIdx.x >> 6, lane = threadIdx.x & 63;
    int m = blockIdx.x * 4 + wave;
    if (m >= NM) return;
    int t = m / NNODES;
    int node = m - t * NNODES;
    int base = t * NNODES;
    int beg = offs[node], end = offs[node + 1];
    int deg = end - beg;
    float ad0 = ald[m * 2 + 0], ad1 = ald[m * 2 + 1];
    float acc;
    if (deg <= 64) {
        int s = 0; float e0 = -INFINITY, e1 = -INFINITY;
        if (lane < deg) {
            s = base + csr[beg + lane];
            e0 = als[s * 2 + 0] + ad0; e0 = e0 > 0.f ? e0 : 0.2f * e0;
            e1 = als[s * 2 + 1] + ad1; e1 = e1 > 0.f ? e1 : 0.2f * e1;
        }
        float m0 = e0, m1 = e1;
        for (int o = 32; o; o >>= 1) {
            m0 = fmaxf(m0, __shfl_xor(m0, o));
            m1 = fmaxf(m1, __shfl_xor(m1, o));
        }
        float ex0 = (lane < deg) ? __expf(e0 - m0) : 0.f;
        float ex1 = (lane < deg) ? __expf(e1 - m1) : 0.f;
        float d0 = ex0, d1 = ex1;
        for (int o = 32; o; o >>= 1) {
            d0 += __shfl_xor(d0, o);
            d1 += __shfl_xor(d1, o);
        }
        ex0 *= 1.f / (d0 + 1e-16f);
        ex1 *= 1.f / (d1 + 1e-16f);
        float a0 = 0.f, a1 = 0.f, a2 = 0.f, a3 = 0.f;
        int i = 0;
        for (; i + 4 <= deg; i += 4) {
            int   s0 = RLI(s, i),     s1 = RLI(s, i + 1), s2 = RLI(s, i + 2), s3 = RLI(s, i + 3);
            float u0 = RL(ex0, i),    v0 = RL(ex1, i);
            float u1 = RL(ex0, i+1),  v1 = RL(ex1, i+1);
            float u2 = RL(ex0, i+2),  v2 = RL(ex1, i+2);
            float u3 = RL(ex0, i+3),  v3 = RL(ex1, i+3);
            a0 += (lane < 32 ? u0 : v0) * xw[(size_t)s0 * 64 + lane];
            a1 += (lane < 32 ? u1 : v1) * xw[(size_t)s1 * 64 + lane];
            a2 += (lane < 32 ? u2 : v2) * xw[(size_t)s2 * 64 + lane];
            a3 += (lane < 32 ? u3 : v3) * xw[(size_t)s3 * 64 + lane];
        }
        for (; i < deg; i++) {
            int s0 = RLI(s, i);
            float u = RL(ex0, i), v = RL(ex1, i);
            a0 += (lane < 32 ? u : v) * xw[(size_t)s0 * 64 + lane];
        }
        acc = (a0 + a1) + (a2 + a3);
    } else {
        float m0 = -INFINITY, m1 = -INFINITY;
        for (int i = beg + lane; i < end; i += 64) {
            int s = base + csr[i];
            float e0 = als[s * 2 + 0] + ad0; e0 = e0 > 0.f ? e0 : 0.2f * e0;
            float e1 = als[s * 2 + 1] + ad1; e1 = e1 > 0.f ? e1 : 0.2f * e1;
            m0 = fmaxf(m0, e0); m1 = fmaxf(m1, e1);
        }
        for (int o = 32; o; o >>= 1) {
            m0 = fmaxf(m0, __shfl_xor(m0, o));
            m1 = fmaxf(m1, __shfl_xor(m1, o));
        }
        float d0 = 0.f, d1 = 0.f;
        for (int i = beg + lane; i < end; i += 64) {
            int s = base + csr[i];
            float e0 = als[s * 2 + 0] + ad0; e0 = e0 > 0.f ? e0 : 0.2f * e0;
            float e1 = als[s * 2 + 1] + ad1; e1 = e1 > 0.f ? e1 : 0.2f * e1;
            d0 += __expf(e0 - m0); d1 += __expf(e1 - m1);
        }
        for (int o = 32; o; o >>= 1) { d0 += __shfl_xor(d0, o); d1 += __shfl_xor(d1, o); }
        float inv0 = 1.f / (d0 + 1e-16f), inv1 = 1.f / (d1 + 1e-16f);
        acc = 0.f;
        for (int i = beg; i < end; i++) {
            int s = base + csr[i];
            float e, wgt;
            if (lane < 32) { e = als[s * 2 + 0] + ad0; e = e > 0.f ? e : 0.2f * e; wgt = __expf(e - m0) * inv0; }
            else           { e = als[s * 2 + 1] + ad1; e = e > 0.f ? e : 0.2f * e; wgt = __expf(e - m1) * inv1; }
            acc += wgt * xw[(size_t)s * 64 + lane];
        }
    }
    float x1v = acc + b[lane];
    x1v = x1v > 0.f ? x1v : expm1f(x1v);
    x1v += xres[(size_t)m * 64 + lane];
    // GAT1 projection: readlane broadcasts
    int j = lane & 31;
    const float* Wp = (lane < 32) ? W1 : Wres1;
    float pacc = 0.f;
#pragma unroll
    for (int k = 0; k < 64; k++) {
        float xv = RL(x1v, k);
        pacc += xv * Wp[k * 32 + j];
    }
    if (lane < 32) xw1[(size_t)m * 32 + j]   = pacc;
    else           xres1[(size_t)m * 32 + j] = pacc;
    float ps = (lane < 32) ? pacc * as1[j]  : 0.f;
    float pd = (lane < 32) ? pacc * ad1v[j] : 0.f;
    for (int o = 16; o; o >>= 1) {
        ps += __shfl_down(ps, o, 32);
        pd += __shfl_down(pd, o, 32);
    }
    if (lane == 0) { als1[m] = ps; ald1[m] = pd; }
}

// ---------------- GAT1 gather -> x2 -> fused GRU0 input projection gi0, ALL timesteps ----------------
__global__ __launch_bounds__(256) void k_gat1_all(const float* __restrict__ xw1,   // [5N,32]
                                                  const float* __restrict__ xres1, // [5N,32]
                                                  const float* __restrict__ als1,  // [5N]
                                                  const float* __restrict__ ald1,  // [5N]
                                                  const int* __restrict__ offs, const int* __restrict__ csr,
                                                  const float* __restrict__ b,     // [32]
                                                  const float* __restrict__ WiT0,  // [32,192] k-major
                                                  const float* __restrict__ bi0,   // [192]
                                                  float* __restrict__ gi0) {
    int wave = threadIdx.x >> 6, lane = threadIdx.x & 63;
    int m = blockIdx.x * 4 + wave;
    if (m >= NM) return;
    int t = m / NNODES;
    int node = m - t * NNODES;
    int base = t * NNODES;
    int beg = offs[node], end = offs[node + 1];
    int deg = end - beg;
    float adv = ald1[m];
    int ch = lane & 31, half = lane >> 5;
    float aggr;
    if (deg <= 64) {
        int s = 0; float e = -INFINITY;
        if (lane < deg) {
            s = base + csr[beg + lane];
            e = als1[s] + adv; e = e > 0.f ? e : 0.2f * e;
        }
        float mx = e;
        for (int o = 32; o; o >>= 1) mx = fmaxf(mx, __shfl_xor(mx, o));
        float ex = (lane < deg) ? __expf(e - mx) : 0.f;
        float d = ex;
        for (int o = 32; o; o >>= 1) d += __shfl_xor(d, o);
        ex *= 1.f / (d + 1e-16f);
        float acc = 0.f;
        for (int i = 0; i < deg; i += 2) {
            int i2 = (i + 1 < deg) ? i + 1 : i;
            int   sa = RLI(s, i),  sb = RLI(s, i2);
            float wa = RL(ex, i),  wb = RL(ex, i2);
            if (i + 1 >= deg) wb = 0.f;
            int   sm = half ? sb : sa;
            float wm = half ? wb : wa;
            acc += wm * xw1[(size_t)sm * 32 + ch];
        }
        acc += __shfl_xor(acc, 32);
        aggr = acc;
    } else {
        float mx = -INFINITY;
        for (int i = beg + lane; i < end; i += 64) {
            float e = als1[base + csr[i]] + adv; e = e > 0.f ? e : 0.2f * e;
            mx = fmaxf(mx, e);
        }
        for (int o = 32; o; o >>= 1) mx = fmaxf(mx, __shfl_xor(mx, o));
        float d = 0.f;
        for (int i = beg + lane; i < end; i += 64) {
            float e = als1[base + csr[i]] + adv; e = e > 0.f ? e : 0.2f * e;
            d += __expf(e - mx);
        }
        for (int o = 32; o; o >>= 1) d += __shfl_xor(d, o);
        float inv = 1.f / (d + 1e-16f);
        float acc = 0.f;
        for (int i = beg; i < end; i++) {
            int s = base + csr[i];
            float e = als1[s] + adv; e = e > 0.f ? e : 0.2f * e;
            float wgt = __expf(e - mx) * inv;
            acc += wgt * xw1[(size_t)s * 32 + ch];
        }
        aggr = acc;
    }
    // x2 value (identical on both wave halves: ch = lane&31)
    float v = aggr + b[ch];
    v = v > 0.f ? v : expm1f(v);
    float x2v = v + xres1[(size_t)m * 32 + ch];
    // gi0 = x2 @ WiT0 + bi0  (lane covers 64 of 192 outputs per pass)
#pragma unroll
    for (int p = 0; p < 3; p++) {
        float accp = bi0[p * 64 + lane];
#pragma unroll 8
        for (int k = 0; k < 32; k++) {
            accp += RL(x2v, k) * WiT0[k * 192 + p * 64 + lane];
        }
        gi0[(size_t)m * 192 + p * 64 + lane] = accp;
    }
}

// ---------------- persistent-LDS GRU chain + head: LDS same-address broadcasts (no readlane in loops) ----------------
// LDS: blob 131072 B (h0rz/h0n/i1rz/i1n/h1rz) + Lh0v 10240 + Lh1v 10240 = 151552 B.
// h1n gate weights (16 KB) come from global (L1-resident).
__global__ __launch_bounds__(512) void k_gruhead_p(const float* __restrict__ gi0,    // [5N,192]
                                                   const float4* __restrict__ wblob, // 131072 B packed
                                                   const float* __restrict__ h1nG,   // [64*64]
                                                   const float* __restrict__ bh0,
                                                   const float* __restrict__ bi1, const float* __restrict__ bh1,
                                                   const float* __restrict__ fc1W, const float* __restrict__ fc1b,
                                                   const float* __restrict__ fc2W, const float* __restrict__ fc2b,
                                                   float* __restrict__ out) {
    extern __shared__ char ldsraw[];
    float2* Lh0rz = (float2*)ldsraw;                 // 32768
    float*  Lh0n  = (float*)(ldsraw + 32768);        // 16384
    float2* Li1rz = (float2*)(ldsraw + 49152);       // 32768
    float*  Li1n  = (float*)(ldsraw + 81920);        // 16384
    float2* Lh1rz = (float2*)(ldsraw + 98304);       // 32768
    float*  Lh0v  = (float*)(ldsraw + 131072);       // 40*64*4 = 10240
    float*  Lh1v  = (float*)(ldsraw + 141312);       // 10240
    int tid = threadIdx.x, wave = tid >> 6, lane = tid & 63;
    int nb0 = wave * GNPW;                           // node base within block
    int node0 = blockIdx.x * GW * GNPW + nb0;        // 250*8*5 = 10000 exactly

    {
        float4* D = (float4*)ldsraw;
#pragma unroll
        for (int i = 0; i < 16; i++) D[tid + i * 512] = wblob[tid + i * 512];
    }
    for (int i = tid; i < GW * GNPW * 64; i += 512) { Lh0v[i] = 0.f; Lh1v[i] = 0.f; }
    __syncthreads();                                 // the only barrier

    float bhr0 = bh0[lane], bhz0 = bh0[64 + lane], bhn0 = bh0[128 + lane];
    float bir1 = bi1[lane] + bh1[lane];
    float biz1 = bi1[64 + lane] + bh1[64 + lane];
    float bin1 = bi1[128 + lane], bhn1 = bh1[128 + lane];

    float h0reg[GNPW] = {0.f, 0.f, 0.f, 0.f, 0.f};   // own-channel copies (for gating)
    float h1reg[GNPW] = {0.f, 0.f, 0.f, 0.f, 0.f};

    for (int t = 0; t < T_STEPS; t++) {
        float gr[GNPW], gz[GNPW], gin[GNPW], ghn[GNPW];
        size_t gb = ((size_t)t * NNODES + node0) * 192;
#pragma unroll
        for (int n = 0; n < GNPW; n++) {
            gr[n]  = gi0[gb + n * 192 + lane] + bhr0;
            gz[n]  = gi0[gb + n * 192 + 64 + lane] + bhz0;
            gin[n] = gi0[gb + n * 192 + 128 + lane];
            ghn[n] = bhn0;
        }
        // GRU0 h-part: weights from LDS, h0 broadcast via same-address LDS reads
#pragma unroll 4
        for (int k = 0; k < 64; k++) {
            float2 wrz = Lh0rz[k * 64 + lane];
            float  wn  = Lh0n[k * 64 + lane];
#pragma unroll
            for (int n = 0; n < GNPW; n++) {
                float hv = Lh0v[(nb0 + n) * 64 + k];   // wave-uniform addr -> broadcast
                gr[n] += hv * wrz.x; gz[n] += hv * wrz.y; ghn[n] += hv * wn;
            }
        }
#pragma unroll
        for (int n = 0; n < GNPW; n++) {
            float r = 1.f / (1.f + __expf(-gr[n]));
            float z = 1.f / (1.f + __expf(-gz[n]));
            float nn = tanhf(gin[n] + r * ghn[n]);
            h0reg[n] = (1.f - z) * nn + z * h0reg[n];
            Lh0v[(nb0 + n) * 64 + lane] = h0reg[n];    // coalesced write (own wave's nodes only)
        }

        // GRU1: x-pass (h0 new) and h-pass (h1 old) fused per-k
#pragma unroll
        for (int n = 0; n < GNPW; n++) { gr[n] = bir1; gz[n] = biz1; gin[n] = bin1; ghn[n] = bhn1; }
#pragma unroll 4
        for (int k = 0; k < 64; k++) {
            float2 wirz = Li1rz[k * 64 + lane];
            float  win  = Li1n[k * 64 + lane];
            float2 whrz = Lh1rz[k * 64 + lane];
            float  whn  = h1nG[k * 64 + lane];         // global, L1-hot
#pragma unroll
            for (int n = 0; n < GNPW; n++) {
                float xv = Lh0v[(nb0 + n) * 64 + k];
                float hv = Lh1v[(nb0 + n) * 64 + k];
                gr[n]  += xv * wirz.x + hv * whrz.x;
                gz[n]  += xv * wirz.y + hv * whrz.y;
                gin[n] += xv * win;
                ghn[n] += hv * whn;
            }
        }
#pragma unroll
        for (int n = 0; n < GNPW; n++) {
            float r = 1.f / (1.f + __expf(-gr[n]));
            float z = 1.f / (1.f + __expf(-gz[n]));
            float nn = tanhf(gin[n] + r * ghn[n]);
            h1reg[n] = (1.f - z) * nn + z * h1reg[n];
            Lh1v[(nb0 + n) * 64 + lane] = h1reg[n];
        }
    }

    // MLP head (readlane on register h1 — small)
    int j = lane & 31, half = lane >> 5;
#pragma unroll
    for (int p = 0; p < 3; p++) {
        int ne = 2 * p;
        int no = (2 * p + 1 < GNPW) ? 2 * p + 1 : 2 * p;
        float a = fc1b[j];
#pragma unroll
        for (int k = 0; k < 64; k++) {
            float he = RL(h1reg[ne], k);
            float ho = RL(h1reg[no], k);
            a += (half ? ho : he) * fc1W[k * 32 + j];
        }
        a = fmaxf(a, 0.f);
        float v = a * fc2W[j];
        for (int o = 16; o; o >>= 1) v += __shfl_down(v, o, 32);
        if ((lane & 31) == 0 && 2 * p + half < GNPW) out[node0 + 2 * p + half] = v + fc2b[0];
    }
}

// ---------------- fallback: per-phase LDS staging (49KB static), flat weights ----------------
__global__ __launch_bounds__(512) void k_gruhead(const float* __restrict__ gi0,
                                                 const float* __restrict__ WhT0,
                                                 const float* __restrict__ WiT1,
                                                 const float* __restrict__ WhT1,
                                                 const float* __restrict__ bh0,
                                                 const float* __restrict__ bi1, const float* __restrict__ bh1,
                                                 const float* __restrict__ fc1W, const float* __restrict__ fc1b,
                                                 const float* __restrict__ fc2W, const float* __restrict__ fc2b,
                                                 float* __restrict__ out) {
    __shared__ float lw[64 * 192];
    int tid = threadIdx.x;
    int wave = tid >> 6, lane = tid & 63;
    int node0 = (blockIdx.x * GW + wave) * GNPW;

    float bhr0 = bh0[lane], bhz0 = bh0[64 + lane], bhn0 = bh0[128 + lane];
    float bir1 = bi1[lane] + bh1[lane];
    float biz1 = bi1[64 + lane] + bh1[64 + lane];
    float bin1 = bi1[128 + lane], bhn1 = bh1[128 + lane];

    float h0[GNPW] = {0.f, 0.f, 0.f, 0.f, 0.f};
    float h1[GNPW] = {0.f, 0.f, 0.f, 0.f, 0.f};

    auto stage = [&](const float* __restrict__ src) {
        __syncthreads();
        const float4* s4 = (const float4*)src;
        float4* d4 = (float4*)lw;
#pragma unroll
        for (int i = 0; i < 6; i++) d4[tid + i * 512] = s4[tid + i * 512];
        __syncthreads();
    };

    for (int t = 0; t < T_STEPS; t++) {
        float gr[GNPW], gz[GNPW], gin[GNPW], ghn[GNPW];
        size_t gb = ((size_t)t * NNODES + node0) * 192;
#pragma unroll
        for (int n = 0; n < GNPW; n++) {
            gr[n]  = gi0[gb + n * 192 + lane] + bhr0;
            gz[n]  = gi0[gb + n * 192 + 64 + lane] + bhz0;
            gin[n] = gi0[gb + n * 192 + 128 + lane];
            ghn[n] = bhn0;
        }
        stage(WhT0);
#pragma unroll 4
        for (int k = 0; k < 64; k++) {
            float wr = lw[k * 192 + lane];
            float wz = lw[k * 192 + 64 + lane];
            float wn = lw[k * 192 + 128 + lane];
#pragma unroll
            for (int n = 0; n < GNPW; n++) {
                float hv = RL(h0[n], k);
                gr[n] += hv * wr; gz[n] += hv * wz; ghn[n] += hv * wn;
            }
        }
#pragma unroll
        for (int n = 0; n < GNPW; n++) {
            float r = 1.f / (1.f + __expf(-gr[n]));
            float z = 1.f / (1.f + __expf(-gz[n]));
            float nn = tanhf(gin[n] + r * ghn[n]);
            h0[n] = (1.f - z) * nn + z * h0[n];
        }
#pragma unroll
        for (int n = 0; n < GNPW; n++) { gr[n] = bir1; gz[n] = biz1; gin[n] = bin1; }
        stage(WiT1);
#pragma unroll 4
        for (int k = 0; k < 64; k++) {
            float wir = lw[k * 192 + lane];
            float wiz = lw[k * 192 + 64 + lane];
            float win = lw[k * 192 + 128 + lane];
#pragma unroll
            for (int n = 0; n < GNPW; n++) {
                float xv = RL(h0[n], k);
                gr[n] += xv * wir; gz[n] += xv * wiz; gin[n] += xv * win;
            }
        }
#pragma unroll
        for (int n = 0; n < GNPW; n++) ghn[n] = bhn1;
        stage(WhT1);
#pragma unroll 4
        for (int k = 0; k < 64; k++) {
            float whr = lw[k * 192 + lane];
            float whz = lw[k * 192 + 64 + lane];
            float whn = lw[k * 192 + 128 + lane];
#pragma unroll
            for (int n = 0; n < GNPW; n++) {
                float hv = RL(h1[n], k);
                gr[n] += hv * whr; gz[n] += hv * whz; ghn[n] += hv * whn;
            }
        }
#pragma unroll
        for (int n = 0; n < GNPW; n++) {
            float r = 1.f / (1.f + __expf(-gr[n]));
            float z = 1.f / (1.f + __expf(-gz[n]));
            float nn = tanhf(gin[n] + r * ghn[n]);
            h1[n] = (1.f - z) * nn + z * h1[n];
        }
    }

    int j = lane & 31, half = lane >> 5;
#pragma unroll
    for (int p = 0; p < 3; p++) {
        int ne = 2 * p;
        int no = (2 * p + 1 < GNPW) ? 2 * p + 1 : 2 * p;
        float a = fc1b[j];
#pragma unroll
        for (int k = 0; k < 64; k++) {
            float he = RL(h1[ne], k);
            float ho = RL(h1[no], k);
            a += (half ? ho : he) * fc1W[k * 32 + j];
        }
        a = fmaxf(a, 0.f);
        float v = a * fc2W[j];
        for (int o = 16; o; o >>= 1) v += __shfl_down(v, o, 32);
        if ((lane & 31) == 0 && 2 * p + half < GNPW) out[node0 + 2 * p + half] = v + fc2b[0];
    }
}

extern "C" void kernel_launch(void* const* d_in, const int* in_sizes, int n_in,
                              void* d_out, int out_size, void* d_ws, size_t ws_size,
                              hipStream_t stream) {
    const float* x_seq   = (const float*)d_in[0];
    const int*   ei      = (const int*)d_in[1];
    const float* gat0_W  = (const float*)d_in[2];
    const float* gat0_as = (const float*)d_in[3];
    const float* gat0_ad = (const float*)d_in[4];
    const float* gat0_b  = (const float*)d_in[5];
    const float* res0_W  = (const float*)d_in[6];
    const float* gat1_W  = (const float*)d_in[7];
    const float* gat1_as = (const float*)d_in[8];
    const float* gat1_ad = (const float*)d_in[9];
    const float* gat1_b  = (const float*)d_in[10];
    const float* res1_W  = (const float*)d_in[11];
    const float* gru0_Wi = (const float*)d_in[12];
    const float* gru0_Wh = (const float*)d_in[13];
    const float* gru0_bi = (const float*)d_in[14];
    const float* gru0_bh = (const float*)d_in[15];
    const float* gru1_Wi = (const float*)d_in[16];
    const float* gru1_Wh = (const float*)d_in[17];
    const float* gru1_bi = (const float*)d_in[18];
    const float* gru1_bh = (const float*)d_in[19];
    const float* fc1_W   = (const float*)d_in[20];
    const float* fc1_b   = (const float*)d_in[21];
    const float* fc2_W   = (const float*)d_in[22];
    const float* fc2_b   = (const float*)d_in[23];
    float* out = (float*)d_out;

    char* w = (char*)d_ws;
    size_t off = 0;
    auto take = [&](size_t bytes) { size_t r = off; off += (bytes + 255) & ~(size_t)255; return r; };
    const size_t N = NNODES, M = NM;
    int*   counts = (int*)(w + take(N * 4));
    int*   cursor = (int*)(w + take(N * 4));
    size_t zero_span = off;                              // counts+cursor contiguous
    int*   offs   = (int*)(w + take((N + 1) * 4));
    int*   csr    = (int*)(w + take((size_t)ETOT * 4));
    float* xw0    = (float*)(w + take(M * 64 * 4));
    float* xres0  = (float*)(w + take(M * 64 * 4));
    float* als0   = (float*)(w + take(M * 2 * 4));
    float* ald0   = (float*)(w + take(M * 2 * 4));
    float* xw1    = (float*)(w + take(M * 32 * 4));
    float* xres1  = (float*)(w + take(M * 32 * 4));
    float* als1   = (float*)(w + take(M * 4));
    float* ald1   = (float*)(w + take(M * 4));
    float* gi0    = (float*)(w + take(M * 192 * 4));   // 38.4 MB
    float* wiT0   = (float*)(w + take(32 * 192 * 4));
    float* whT0   = (float*)(w + take(64 * 192 * 4));
    float* wiT1   = (float*)(w + take(64 * 192 * 4));
    float* whT1   = (float*)(w + take(64 * 192 * 4));
    // packed blob: h0rz|h0n|i1rz|i1n|h1rz contiguous (131072 B); h1n separate
    char*   blob  = w + take(131072);
    float2* h0rz  = (float2*)blob;
    float*  h0n   = (float*)(blob + 32768);
    float2* i1rz  = (float2*)(blob + 49152);
    float*  i1n   = (float*)(blob + 81920);
    float2* h1rz  = (float2*)(blob + 98304);
    float*  h1n   = (float*)(w + take(4096 * 4));

    // CSR build + weight transpose (once per launch; ws re-poisoned each call)
    hipMemsetAsync(w, 0, zero_span, stream);            // counts + cursor in one memset
    const int egrid = (ETOT + 255) / 256;
    k_count<<<egrid, 256, 0, stream>>>(ei, counts);
    k_scan<<<1, 1024, 0, stream>>>(counts, offs);
    k_fill<<<egrid, 256, 0, stream>>>(ei, offs, cursor, csr);
    const int ttot = 6144 + 3 * 12288 + 3 * 4096;       // 55296
    k_transpose<<<(ttot + 255) / 256, 256, 0, stream>>>(gru0_Wi, gru0_Wh, gru1_Wi, gru1_Wh,
                                                        wiT0, whT0, wiT1, whT1,
                                                        h0rz, h0n, i1rz, i1n, h1rz, h1n);

    // Batched GAT phases over all 5 timesteps (independent of recurrence)
    const int mgrid = (NM + 3) / 4;   // 12500 blocks
    k_mm0_all<<<mgrid, 256, 0, stream>>>(x_seq, gat0_W, res0_W, gat0_as, gat0_ad, xw0, xres0, als0, ald0);
    k_gat0_all<<<mgrid, 256, 0, stream>>>(xw0, xres0, als0, ald0, offs, csr, gat0_b,
                                          gat1_W, res1_W, gat1_as, gat1_ad,
                                          xw1, xres1, als1, ald1);
    k_gat1_all<<<mgrid, 256, 0, stream>>>(xw1, xres1, als1, ald1, offs, csr, gat1_b,
                                          wiT0, gru0_bi, gi0);

    // Recurrent chain + head: prefer persistent-LDS variant (151552 B dyn shared)
    const int ggrid = NNODES / (GW * GNPW);   // 250
    hipError_t ae = hipFuncSetAttribute(reinterpret_cast<const void*>(k_gruhead_p),
                                        hipFuncAttributeMaxDynamicSharedMemorySize, 151552);
    if (ae == hipSuccess) {
        k_gruhead_p<<<ggrid, 512, 151552, stream>>>(gi0, (const float4*)blob, h1n,
                                                    gru0_bh, gru1_bi, gru1_bh,
                                                    fc1_W, fc1_b, fc2_W, fc2_b, out);
    } else {
        k_gruhead<<<ggrid, 512, 0, stream>>>(gi0, whT0, wiT1, whT1,
                                             gru0_bh, gru1_bi, gru1_bh,
                                             fc1_W, fc1_b, fc2_W, fc2_b, out);
    }
}

// Round 13
// 368.041 us; speedup vs baseline: 1.0732x; 1.0732x over previous
//
#include <hip/hip_runtime.h>
#include <hip/hip_bf16.h>
#include <math.h>

#define T_STEPS 5
#define NNODES  10000
#define NM      (T_STEPS * NNODES)   // 50000 node-instances (t,n)
#define F_IN    16
#define NEDGES  160000
#define ETOT    (NEDGES + NNODES)    // + self loops
#define GW      8                    // waves per block in gruhead (512 threads)
#define GNPW    5                    // nodes per wave: 8*5=40 nodes/block, 250 blocks

// grid partition for the fused preamble kernel
#define CNT_BLKS 665                 // ceil(ETOT/256)
#define TRN_BLKS 216                 // 55296/256
#define MM0_BLKS 12500               // ceil(NM/4)

// SGPR broadcast: readlane — index MUST be wave-uniform
#define RL(v, k)  __int_as_float(__builtin_amdgcn_readlane(__float_as_int(v), (k)))
#define RLI(v, k) __builtin_amdgcn_readlane((v), (k))

// ---------------- CSR scan + fill ----------------
__global__ __launch_bounds__(1024) void k_scan(const int* __restrict__ counts, int* __restrict__ offs) {
    __shared__ int ssum[1024];
    int t = threadIdx.x;
    const int chunk = (NNODES + 1023) / 1024;
    int start = t * chunk, end = min(start + chunk, NNODES);
    int s = 0;
    for (int i = start; i < end; i++) s += counts[i];
    ssum[t] = s;
    __syncthreads();
    for (int off = 1; off < 1024; off <<= 1) {
        int v = (t >= off) ? ssum[t - off] : 0;
        __syncthreads();
        ssum[t] += v;
        __syncthreads();
    }
    int excl = (t == 0) ? 0 : ssum[t - 1];
    for (int i = start; i < end; i++) { offs[i] = excl; excl += counts[i]; }
    if (t == 1023) offs[NNODES] = ssum[1023];
}

__global__ __launch_bounds__(256) void k_fill(const int* __restrict__ ei, const int* __restrict__ offs,
                                              int* __restrict__ cursor, int* __restrict__ csr) {
    int idx = blockIdx.x * 256 + threadIdx.x;
    if (idx >= ETOT) return;
    int src, dst;
    if (idx < NEDGES) { src = ei[idx]; dst = ei[NEDGES + idx]; }
    else              { src = dst = idx - NEDGES; }
    int p = atomicAdd(&cursor[dst], 1);
    csr[offs[dst] + p] = src;
}

// ---------------- fused preamble: edge count | weight transpose | GAT0 projections ----------------
// blob layout (147456 B): h0rz@0 | h0n@32768 | i1rz@49152 | i1n@81920 | h1rz@98304 | h1n@131072
__global__ __launch_bounds__(256) void k_preamble(const int* __restrict__ ei, int* __restrict__ counts,
                                                  const float* __restrict__ Wi0, const float* __restrict__ Wh0,
                                                  const float* __restrict__ Wi1, const float* __restrict__ Wh1,
                                                  float* __restrict__ WiT0, float* __restrict__ WhT0,
                                                  float* __restrict__ WiT1, float* __restrict__ WhT1,
                                                  float2* __restrict__ h0rz, float* __restrict__ h0n,
                                                  float2* __restrict__ i1rz, float* __restrict__ i1n,
                                                  float2* __restrict__ h1rz, float* __restrict__ h1n,
                                                  const float* __restrict__ x,     // [5N,16]
                                                  const float* __restrict__ W,    // [16,64]
                                                  const float* __restrict__ Wres, // [16,64]
                                                  const float* __restrict__ asrc, const float* __restrict__ adst,
                                                  float* __restrict__ xw, float* __restrict__ xres,
                                                  float* __restrict__ als, float* __restrict__ ald) {
    int b = blockIdx.x;
    if (b < CNT_BLKS) {
        int idx = b * 256 + threadIdx.x;
        if (idx >= ETOT) return;
        int dst = (idx < NEDGES) ? ei[NEDGES + idx] : (idx - NEDGES);
        atomicAdd(&counts[dst], 1);
        return;
    }
    if (b < CNT_BLKS + TRN_BLKS) {
        int idx = (b - CNT_BLKS) * 256 + threadIdx.x;
        if (idx < 6144)  { int k = idx / 192, r = idx % 192; WiT0[idx] = Wi0[r * 32 + k]; return; }
        idx -= 6144;
        if (idx < 12288) { int k = idx / 192, r = idx % 192; WhT0[idx] = Wh0[r * 64 + k]; return; }
        idx -= 12288;
        if (idx < 12288) { int k = idx / 192, r = idx % 192; WiT1[idx] = Wi1[r * 64 + k]; return; }
        idx -= 12288;
        if (idx < 12288) { int k = idx / 192, r = idx % 192; WhT1[idx] = Wh1[r * 64 + k]; return; }
        idx -= 12288;
        if (idx < 4096) { int k = idx >> 6, c = idx & 63;
                          h0rz[idx] = make_float2(Wh0[c * 64 + k], Wh0[(64 + c) * 64 + k]);
                          h0n[idx]  = Wh0[(128 + c) * 64 + k]; return; }
        idx -= 4096;
        if (idx < 4096) { int k = idx >> 6, c = idx & 63;
                          i1rz[idx] = make_float2(Wi1[c * 64 + k], Wi1[(64 + c) * 64 + k]);
                          i1n[idx]  = Wi1[(128 + c) * 64 + k]; return; }
        idx -= 4096;
        if (idx < 4096) { int k = idx >> 6, c = idx & 63;
                          h1rz[idx] = make_float2(Wh1[c * 64 + k], Wh1[(64 + c) * 64 + k]);
                          h1n[idx]  = Wh1[(128 + c) * 64 + k]; }
        return;
    }
    // ---- GAT0 projections (all timesteps) ----
    int wave = threadIdx.x >> 6, lane = threadIdx.x & 63;
    int m = (b - CNT_BLKS - TRN_BLKS) * 4 + wave;
    if (m >= NM) return;
    const float* xr = x + (size_t)m * F_IN;
    float xreg[F_IN];
#pragma unroll
    for (int k = 0; k < F_IN; k++) xreg[k] = xr[k];
    float acc = 0.f, accr = 0.f;
#pragma unroll
    for (int k = 0; k < F_IN; k++) {
        acc  += xreg[k] * W[k * 64 + lane];
        accr += xreg[k] * Wres[k * 64 + lane];
    }
    xw[(size_t)m * 64 + lane]   = acc;
    xres[(size_t)m * 64 + lane] = accr;
    float ps = acc * asrc[lane], pd = acc * adst[lane];
    for (int off = 16; off; off >>= 1) {
        ps += __shfl_down(ps, off, 32);
        pd += __shfl_down(pd, off, 32);
    }
    if ((lane & 31) == 0) {
        int h = lane >> 5;
        als[m * 2 + h] = ps;
        ald[m * 2 + h] = pd;
    }
}

// ---------------- fused GAT0 gather + ELU + residual + GAT1 projection, ALL timesteps ----------------
__global__ __launch_bounds__(256) void k_gat0_all(const float* __restrict__ xw,   // [5N,64]
                                                  const float* __restrict__ xres, // [5N,64]
                                                  const float* __restrict__ als,  // [5N,2]
                                                  const float* __restrict__ ald,  // [5N,2]
                                                  const int* __restrict__ offs, const int* __restrict__ csr,
                                                  const float* __restrict__ b,    // [64]
                                                  const float* __restrict__ W1,   // [64,32]
                                                  const float* __restrict__ Wres1,// [64,32]
                                                  const float* __restrict__ as1,  // [32]
                                                  const float* __restrict__ ad1v, // [32]
                                                  float* __restrict__ xw1, float* __restrict__ xres1,
                                                  float* __restrict__ als1, float* __restrict__ ald1) {
    int wave = threadIdx.x >> 6, lane = threadIdx.x & 63;
    int m = blockIdx.x * 4 + wave;
    if (m >= NM) return;
    int t = m / NNODES;
    int node = m - t * NNODES;
    int base = t * NNODES;
    int beg = offs[node], end = offs[node + 1];
    int deg = end - beg;
    float ad0 = ald[m * 2 + 0], ad1 = ald[m * 2 + 1];
    float acc;
    if (deg <= 64) {
        int s = 0; float e0 = -INFINITY, e1 = -INFINITY;
        if (lane < deg) {
            s = base + csr[beg + lane];
            e0 = als[s * 2 + 0] + ad0; e0 = e0 > 0.f ? e0 : 0.2f * e0;
            e1 = als[s * 2 + 1] + ad1; e1 = e1 > 0.f ? e1 : 0.2f * e1;
        }
        float m0 = e0, m1 = e1;
        for (int o = 32; o; o >>= 1) {
            m0 = fmaxf(m0, __shfl_xor(m0, o));
            m1 = fmaxf(m1, __shfl_xor(m1, o));
        }
        float ex0 = (lane < deg) ? __expf(e0 - m0) : 0.f;
        float ex1 = (lane < deg) ? __expf(e1 - m1) : 0.f;
        float d0 = ex0, d1 = ex1;
        for (int o = 32; o; o >>= 1) {
            d0 += __shfl_xor(d0, o);
            d1 += __shfl_xor(d1, o);
        }
        ex0 *= 1.f / (d0 + 1e-16f);
        ex1 *= 1.f / (d1 + 1e-16f);
        // aggregation: 8 independent gathers in flight per iteration (all RL indices uniform)
        float a0 = 0.f, a1 = 0.f, a2 = 0.f, a3 = 0.f;
        int i = 0;
        for (; i + 8 <= deg; i += 8) {
            int   s0 = RLI(s, i),    s1 = RLI(s, i+1), s2 = RLI(s, i+2), s3 = RLI(s, i+3);
            int   s4 = RLI(s, i+4),  s5 = RLI(s, i+5), s6 = RLI(s, i+6), s7 = RLI(s, i+7);
            float x0 = xw[(size_t)s0 * 64 + lane];
            float x1 = xw[(size_t)s1 * 64 + lane];
            float x2 = xw[(size_t)s2 * 64 + lane];
            float x3 = xw[(size_t)s3 * 64 + lane];
            float x4 = xw[(size_t)s4 * 64 + lane];
            float x5 = xw[(size_t)s5 * 64 + lane];
            float x6 = xw[(size_t)s6 * 64 + lane];
            float x7 = xw[(size_t)s7 * 64 + lane];
            float u0 = (lane < 32) ? RL(ex0, i)   : RL(ex1, i);
            float u1 = (lane < 32) ? RL(ex0, i+1) : RL(ex1, i+1);
            float u2 = (lane < 32) ? RL(ex0, i+2) : RL(ex1, i+2);
            float u3 = (lane < 32) ? RL(ex0, i+3) : RL(ex1, i+3);
            float u4 = (lane < 32) ? RL(ex0, i+4) : RL(ex1, i+4);
            float u5 = (lane < 32) ? RL(ex0, i+5) : RL(ex1, i+5);
            float u6 = (lane < 32) ? RL(ex0, i+6) : RL(ex1, i+6);
            float u7 = (lane < 32) ? RL(ex0, i+7) : RL(ex1, i+7);
            a0 += u0 * x0 + u4 * x4;
            a1 += u1 * x1 + u5 * x5;
            a2 += u2 * x2 + u6 * x6;
            a3 += u3 * x3 + u7 * x7;
        }
        for (; i < deg; i++) {
            int s0 = RLI(s, i);
            float u = (lane < 32) ? RL(ex0, i) : RL(ex1, i);
            a0 += u * xw[(size_t)s0 * 64 + lane];
        }
        acc = (a0 + a1) + (a2 + a3);
    } else {
        float m0 = -INFINITY, m1 = -INFINITY;
        for (int i = beg + lane; i < end; i += 64) {
            int s = base + csr[i];
            float e0 = als[s * 2 + 0] + ad0; e0 = e0 > 0.f ? e0 : 0.2f * e0;
            float e1 = als[s * 2 + 1] + ad1; e1 = e1 > 0.f ? e1 : 0.2f * e1;
            m0 = fmaxf(m0, e0); m1 = fmaxf(m1, e1);
        }
        for (int o = 32; o; o >>= 1) {
            m0 = fmaxf(m0, __shfl_xor(m0, o));
            m1 = fmaxf(m1, __shfl_xor(m1, o));
        }
        float d0 = 0.f, d1 = 0.f;
        for (int i = beg + lane; i < end; i += 64) {
            int s = base + csr[i];
            float e0 = als[s * 2 + 0] + ad0; e0 = e0 > 0.f ? e0 : 0.2f * e0;
            float e1 = als[s * 2 + 1] + ad1; e1 = e1 > 0.f ? e1 : 0.2f * e1;
            d0 += __expf(e0 - m0); d1 += __expf(e1 - m1);
        }
        for (int o = 32; o; o >>= 1) { d0 += __shfl_xor(d0, o); d1 += __shfl_xor(d1, o); }
        float inv0 = 1.f / (d0 + 1e-16f), inv1 = 1.f / (d1 + 1e-16f);
        acc = 0.f;
        for (int i = beg; i < end; i++) {
            int s = base + csr[i];
            float e, wgt;
            if (lane < 32) { e = als[s * 2 + 0] + ad0; e = e > 0.f ? e : 0.2f * e; wgt = __expf(e - m0) * inv0; }
            else           { e = als[s * 2 + 1] + ad1; e = e > 0.f ? e : 0.2f * e; wgt = __expf(e - m1) * inv1; }
            acc += wgt * xw[(size_t)s * 64 + lane];
        }
    }
    float x1v = acc + b[lane];
    x1v = x1v > 0.f ? x1v : expm1f(x1v);
    x1v += xres[(size_t)m * 64 + lane];
    // GAT1 projection: readlane broadcasts
    int j = lane & 31;
    const float* Wp = (lane < 32) ? W1 : Wres1;
    float pacc = 0.f;
#pragma unroll
    for (int k = 0; k < 64; k++) {
        float xv = RL(x1v, k);
        pacc += xv * Wp[k * 32 + j];
    }
    if (lane < 32) xw1[(size_t)m * 32 + j]   = pacc;
    else           xres1[(size_t)m * 32 + j] = pacc;
    float ps = (lane < 32) ? pacc * as1[j]  : 0.f;
    float pd = (lane < 32) ? pacc * ad1v[j] : 0.f;
    for (int o = 16; o; o >>= 1) {
        ps += __shfl_down(ps, o, 32);
        pd += __shfl_down(pd, o, 32);
    }
    if (lane == 0) { als1[m] = ps; ald1[m] = pd; }
}

// ---------------- GAT1 gather -> x2 -> fused GRU0 input projection gi0, ALL timesteps ----------------
__global__ __launch_bounds__(256) void k_gat1_all(const float* __restrict__ xw1,   // [5N,32]
                                                  const float* __restrict__ xres1, // [5N,32]
                                                  const float* __restrict__ als1,  // [5N]
                                                  const float* __restrict__ ald1,  // [5N]
                                                  const int* __restrict__ offs, const int* __restrict__ csr,
                                                  const float* __restrict__ b,     // [32]
                                                  const float* __restrict__ WiT0,  // [32,192] k-major
                                                  const float* __restrict__ bi0,   // [192]
                                                  float* __restrict__ gi0) {
    int wave = threadIdx.x >> 6, lane = threadIdx.x & 63;
    int m = blockIdx.x * 4 + wave;
    if (m >= NM) return;
    int t = m / NNODES;
    int node = m - t * NNODES;
    int base = t * NNODES;
    int beg = offs[node], end = offs[node + 1];
    int deg = end - beg;
    float adv = ald1[m];
    int ch = lane & 31, half = lane >> 5;
    float aggr;
    if (deg <= 64) {
        int s = 0; float e = -INFINITY;
        if (lane < deg) {
            s = base + csr[beg + lane];
            e = als1[s] + adv; e = e > 0.f ? e : 0.2f * e;
        }
        float mx = e;
        for (int o = 32; o; o >>= 1) mx = fmaxf(mx, __shfl_xor(mx, o));
        float ex = (lane < deg) ? __expf(e - mx) : 0.f;
        float d = ex;
        for (int o = 32; o; o >>= 1) d += __shfl_xor(d, o);
        ex *= 1.f / (d + 1e-16f);
        // 8 edges per iteration: uniform readlanes for all 8, per-half SELECT (legal)
        float acc0 = 0.f, acc1 = 0.f;
        int i = 0;
        for (; i + 8 <= deg; i += 8) {
            int   e0 = RLI(s, i),   o0 = RLI(s, i+1);
            int   e1 = RLI(s, i+2), o1 = RLI(s, i+3);
            int   e2 = RLI(s, i+4), o2 = RLI(s, i+5);
            int   e3 = RLI(s, i+6), o3 = RLI(s, i+7);
            int   sa0 = half ? o0 : e0, sa1 = half ? o1 : e1;
            int   sa2 = half ? o2 : e2, sa3 = half ? o3 : e3;
            float xa0 = xw1[(size_t)sa0 * 32 + ch];
            float xa1 = xw1[(size_t)sa1 * 32 + ch];
            float xa2 = xw1[(size_t)sa2 * 32 + ch];
            float xa3 = xw1[(size_t)sa3 * 32 + ch];
            float we0 = RL(ex, i),   wo0 = RL(ex, i+1);
            float we1 = RL(ex, i+2), wo1 = RL(ex, i+3);
            float we2 = RL(ex, i+4), wo2 = RL(ex, i+5);
            float we3 = RL(ex, i+6), wo3 = RL(ex, i+7);
            float wa0 = half ? wo0 : we0, wa1 = half ? wo1 : we1;
            float wa2 = half ? wo2 : we2, wa3 = half ? wo3 : we3;
            acc0 += wa0 * xa0 + wa2 * xa2;
            acc1 += wa1 * xa1 + wa3 * xa3;
        }
        for (; i < deg; i += 2) {
            int i2 = (i + 1 < deg) ? i + 1 : i;
            int   sa = RLI(s, i),  sb = RLI(s, i2);
            float wa = RL(ex, i),  wb = RL(ex, i2);
            if (i + 1 >= deg) wb = 0.f;
            int   sm = half ? sb : sa;
            float wm = half ? wb : wa;
            acc0 += wm * xw1[(size_t)sm * 32 + ch];
        }
        float acc = acc0 + acc1;
        acc += __shfl_xor(acc, 32);
        aggr = acc;
    } else {
        float mx = -INFINITY;
        for (int i = beg + lane; i < end; i += 64) {
            float e = als1[base + csr[i]] + adv; e = e > 0.f ? e : 0.2f * e;
            mx = fmaxf(mx, e);
        }
        for (int o = 32; o; o >>= 1) mx = fmaxf(mx, __shfl_xor(mx, o));
        float d = 0.f;
        for (int i = beg + lane; i < end; i += 64) {
            float e = als1[base + csr[i]] + adv; e = e > 0.f ? e : 0.2f * e;
            d += __expf(e - mx);
        }
        for (int o = 32; o; o >>= 1) d += __shfl_xor(d, o);
        float inv = 1.f / (d + 1e-16f);
        float acc = 0.f;
        for (int i = beg; i < end; i++) {
            int s = base + csr[i];
            float e = als1[s] + adv; e = e > 0.f ? e : 0.2f * e;
            float wgt = __expf(e - mx) * inv;
            acc += wgt * xw1[(size_t)s * 32 + ch];
        }
        aggr = acc;
    }
    // x2 value (identical on both wave halves: ch = lane&31)
    float v = aggr + b[ch];
    v = v > 0.f ? v : expm1f(v);
    float x2v = v + xres1[(size_t)m * 32 + ch];
    // gi0 = x2 @ WiT0 + bi0  (lane covers 64 of 192 outputs per pass)
#pragma unroll
    for (int p = 0; p < 3; p++) {
        float accp = bi0[p * 64 + lane];
#pragma unroll 8
        for (int k = 0; k < 32; k++) {
            accp += RL(x2v, k) * WiT0[k * 192 + p * 64 + lane];
        }
        gi0[(size_t)m * 192 + p * 64 + lane] = accp;
    }
}

// ---------------- persistent-LDS GRU chain + head (round-10 version: RL broadcasts, 2 DS/k) ----------------
__global__ __launch_bounds__(512) void k_gruhead_p(const float* __restrict__ gi0,    // [5N,192]
                                                   const float4* __restrict__ wblob, // packed weights, 147456 B
                                                   const float* __restrict__ bh0,
                                                   const float* __restrict__ bi1, const float* __restrict__ bh1,
                                                   const float* __restrict__ fc1W, const float* __restrict__ fc1b,
                                                   const float* __restrict__ fc2W, const float* __restrict__ fc2b,
                                                   float* __restrict__ out) {
    extern __shared__ char ldsraw[];                // 147456 B
    float2* Lh0rz = (float2*)ldsraw;                // 32768
    float*  Lh0n  = (float*)(ldsraw + 32768);       // 16384
    float2* Li1rz = (float2*)(ldsraw + 49152);
    float*  Li1n  = (float*)(ldsraw + 81920);
    float2* Lh1rz = (float2*)(ldsraw + 98304);
    float*  Lh1n  = (float*)(ldsraw + 131072);
    int tid = threadIdx.x, wave = tid >> 6, lane = tid & 63;
    int node0 = (blockIdx.x * GW + wave) * GNPW;    // 250*8*5 = 10000 exactly

    {
        float4* D = (float4*)ldsraw;
#pragma unroll
        for (int i = 0; i < 18; i++) D[tid + i * 512] = wblob[tid + i * 512];
    }
    __syncthreads();                                // the only barrier

    float bhr0 = bh0[lane], bhz0 = bh0[64 + lane], bhn0 = bh0[128 + lane];
    float bir1 = bi1[lane] + bh1[lane];
    float biz1 = bi1[64 + lane] + bh1[64 + lane];
    float bin1 = bi1[128 + lane], bhn1 = bh1[128 + lane];

    float h0[GNPW] = {0.f, 0.f, 0.f, 0.f, 0.f};
    float h1[GNPW] = {0.f, 0.f, 0.f, 0.f, 0.f};

    for (int t = 0; t < T_STEPS; t++) {
        float gr[GNPW], gz[GNPW], gin[GNPW], ghn[GNPW];
        size_t gb = ((size_t)t * NNODES + node0) * 192;
#pragma unroll
        for (int n = 0; n < GNPW; n++) {
            gr[n]  = gi0[gb + n * 192 + lane] + bhr0;
            gz[n]  = gi0[gb + n * 192 + 64 + lane] + bhz0;
            gin[n] = gi0[gb + n * 192 + 128 + lane];
            ghn[n] = bhn0;
        }
        // GRU0 h-part (K=64): 2 DS reads per k
#pragma unroll 4
        for (int k = 0; k < 64; k++) {
            float2 wrz = Lh0rz[k * 64 + lane];
            float  wn  = Lh0n[k * 64 + lane];
#pragma unroll
            for (int n = 0; n < GNPW; n++) {
                float hv = RL(h0[n], k);
                gr[n] += hv * wrz.x; gz[n] += hv * wrz.y; ghn[n] += hv * wn;
            }
        }
#pragma unroll
        for (int n = 0; n < GNPW; n++) {
            float r = 1.f / (1.f + __expf(-gr[n]));
            float z = 1.f / (1.f + __expf(-gz[n]));
            float nn = tanhf(gin[n] + r * ghn[n]);
            h0[n] = (1.f - z) * nn + z * h0[n];
        }

        // GRU1 x-pass (x = h0 new)
#pragma unroll
        for (int n = 0; n < GNPW; n++) { gr[n] = bir1; gz[n] = biz1; gin[n] = bin1; }
#pragma unroll 4
        for (int k = 0; k < 64; k++) {
            float2 wrz = Li1rz[k * 64 + lane];
            float  wn  = Li1n[k * 64 + lane];
#pragma unroll
            for (int n = 0; n < GNPW; n++) {
                float xv = RL(h0[n], k);
                gr[n] += xv * wrz.x; gz[n] += xv * wrz.y; gin[n] += xv * wn;
            }
        }
        // GRU1 h-pass
#pragma unroll
        for (int n = 0; n < GNPW; n++) ghn[n] = bhn1;
#pragma unroll 4
        for (int k = 0; k < 64; k++) {
            float2 wrz = Lh1rz[k * 64 + lane];
            float  wn  = Lh1n[k * 64 + lane];
#pragma unroll
            for (int n = 0; n < GNPW; n++) {
                float hv = RL(h1[n], k);
                gr[n] += hv * wrz.x; gz[n] += hv * wrz.y; ghn[n] += hv * wn;
            }
        }
#pragma unroll
        for (int n = 0; n < GNPW; n++) {
            float r = 1.f / (1.f + __expf(-gr[n]));
            float z = 1.f / (1.f + __expf(-gz[n]));
            float nn = tanhf(gin[n] + r * ghn[n]);
            h1[n] = (1.f - z) * nn + z * h1[n];
        }
    }

    // MLP head
    int j = lane & 31, half = lane >> 5;
#pragma unroll
    for (int p = 0; p < 3; p++) {
        int ne = 2 * p;
        int no = (2 * p + 1 < GNPW) ? 2 * p + 1 : 2 * p;
        float a = fc1b[j];
#pragma unroll
        for (int k = 0; k < 64; k++) {
            float he = RL(h1[ne], k);
            float ho = RL(h1[no], k);
            a += (half ? ho : he) * fc1W[k * 32 + j];
        }
        a = fmaxf(a, 0.f);
        float v = a * fc2W[j];
        for (int o = 16; o; o >>= 1) v += __shfl_down(v, o, 32);
        if ((lane & 31) == 0 && 2 * p + half < GNPW) out[node0 + 2 * p + half] = v + fc2b[0];
    }
}

// ---------------- fallback: per-phase LDS staging (49KB static), flat weights ----------------
__global__ __launch_bounds__(512) void k_gruhead(const float* __restrict__ gi0,
                                                 const float* __restrict__ WhT0,
                                                 const float* __restrict__ WiT1,
                                                 const float* __restrict__ WhT1,
                                                 const float* __restrict__ bh0,
                                                 const float* __restrict__ bi1, const float* __restrict__ bh1,
                                                 const float* __restrict__ fc1W, const float* __restrict__ fc1b,
                                                 const float* __restrict__ fc2W, const float* __restrict__ fc2b,
                                                 float* __restrict__ out) {
    __shared__ float lw[64 * 192];
    int tid = threadIdx.x;
    int wave = tid >> 6, lane = tid & 63;
    int node0 = (blockIdx.x * GW + wave) * GNPW;

    float bhr0 = bh0[lane], bhz0 = bh0[64 + lane], bhn0 = bh0[128 + lane];
    float bir1 = bi1[lane] + bh1[lane];
    float biz1 = bi1[64 + lane] + bh1[64 + lane];
    float bin1 = bi1[128 + lane], bhn1 = bh1[128 + lane];

    float h0[GNPW] = {0.f, 0.f, 0.f, 0.f, 0.f};
    float h1[GNPW] = {0.f, 0.f, 0.f, 0.f, 0.f};

    auto stage = [&](const float* __restrict__ src) {
        __syncthreads();
        const float4* s4 = (const float4*)src;
        float4* d4 = (float4*)lw;
#pragma unroll
        for (int i = 0; i < 6; i++) d4[tid + i * 512] = s4[tid + i * 512];
        __syncthreads();
    };

    for (int t = 0; t < T_STEPS; t++) {
        float gr[GNPW], gz[GNPW], gin[GNPW], ghn[GNPW];
        size_t gb = ((size_t)t * NNODES + node0) * 192;
#pragma unroll
        for (int n = 0; n < GNPW; n++) {
            gr[n]  = gi0[gb + n * 192 + lane] + bhr0;
            gz[n]  = gi0[gb + n * 192 + 64 + lane] + bhz0;
            gin[n] = gi0[gb + n * 192 + 128 + lane];
            ghn[n] = bhn0;
        }
        stage(WhT0);
#pragma unroll 4
        for (int k = 0; k < 64; k++) {
            float wr = lw[k * 192 + lane];
            float wz = lw[k * 192 + 64 + lane];
            float wn = lw[k * 192 + 128 + lane];
#pragma unroll
            for (int n = 0; n < GNPW; n++) {
                float hv = RL(h0[n], k);
                gr[n] += hv * wr; gz[n] += hv * wz; ghn[n] += hv * wn;
            }
        }
#pragma unroll
        for (int n = 0; n < GNPW; n++) {
            float r = 1.f / (1.f + __expf(-gr[n]));
            float z = 1.f / (1.f + __expf(-gz[n]));
            float nn = tanhf(gin[n] + r * ghn[n]);
            h0[n] = (1.f - z) * nn + z * h0[n];
        }
#pragma unroll
        for (int n = 0; n < GNPW; n++) { gr[n] = bir1; gz[n] = biz1; gin[n] = bin1; }
        stage(WiT1);
#pragma unroll 4
        for (int k = 0; k < 64; k++) {
            float wir = lw[k * 192 + lane];
            float wiz = lw[k * 192 + 64 + lane];
            float win = lw[k * 192 + 128 + lane];
#pragma unroll
            for (int n = 0; n < GNPW; n++) {
                float xv = RL(h0[n], k);
                gr[n] += xv * wir; gz[n] += xv * wiz; gin[n] += xv * win;
            }
        }
#pragma unroll
        for (int n = 0; n < GNPW; n++) ghn[n] = bhn1;
        stage(WhT1);
#pragma unroll 4
        for (int k = 0; k < 64; k++) {
            float whr = lw[k * 192 + lane];
            float whz = lw[k * 192 + 64 + lane];
            float whn = lw[k * 192 + 128 + lane];
#pragma unroll
            for (int n = 0; n < GNPW; n++) {
                float hv = RL(h1[n], k);
                gr[n] += hv * whr; gz[n] += hv * whz; ghn[n] += hv * whn;
            }
        }
#pragma unroll
        for (int n = 0; n < GNPW; n++) {
            float r = 1.f / (1.f + __expf(-gr[n]));
            float z = 1.f / (1.f + __expf(-gz[n]));
            float nn = tanhf(gin[n] + r * ghn[n]);
            h1[n] = (1.f - z) * nn + z * h1[n];
        }
    }

    int j = lane & 31, half = lane >> 5;
#pragma unroll
    for (int p = 0; p < 3; p++) {
        int ne = 2 * p;
        int no = (2 * p + 1 < GNPW) ? 2 * p + 1 : 2 * p;
        float a = fc1b[j];
#pragma unroll
        for (int k = 0; k < 64; k++) {
            float he = RL(h1[ne], k);
            float ho = RL(h1[no], k);
            a += (half ? ho : he) * fc1W[k * 32 + j];
        }
        a = fmaxf(a, 0.f);
        float v = a * fc2W[j];
        for (int o = 16; o; o >>= 1) v += __shfl_down(v, o, 32);
        if ((lane & 31) == 0 && 2 * p + half < GNPW) out[node0 + 2 * p + half] = v + fc2b[0];
    }
}

extern "C" void kernel_launch(void* const* d_in, const int* in_sizes, int n_in,
                              void* d_out, int out_size, void* d_ws, size_t ws_size,
                              hipStream_t stream) {
    const float* x_seq   = (const float*)d_in[0];
    const int*   ei      = (const int*)d_in[1];
    const float* gat0_W  = (const float*)d_in[2];
    const float* gat0_as = (const float*)d_in[3];
    const float* gat0_ad = (const float*)d_in[4];
    const float* gat0_b  = (const float*)d_in[5];
    const float* res0_W  = (const float*)d_in[6];
    const float* gat1_W  = (const float*)d_in[7];
    const float* gat1_as = (const float*)d_in[8];
    const float* gat1_ad = (const float*)d_in[9];
    const float* gat1_b  = (const float*)d_in[10];
    const float* res1_W  = (const float*)d_in[11];
    const float* gru0_Wi = (const float*)d_in[12];
    const float* gru0_Wh = (const float*)d_in[13];
    const float* gru0_bi = (const float*)d_in[14];
    const float* gru0_bh = (const float*)d_in[15];
    const float* gru1_Wi = (const float*)d_in[16];
    const float* gru1_Wh = (const float*)d_in[17];
    const float* gru1_bi = (const float*)d_in[18];
    const float* gru1_bh = (const float*)d_in[19];
    const float* fc1_W   = (const float*)d_in[20];
    const float* fc1_b   = (const float*)d_in[21];
    const float* fc2_W   = (const float*)d_in[22];
    const float* fc2_b   = (const float*)d_in[23];
    float* out = (float*)d_out;

    char* w = (char*)d_ws;
    size_t off = 0;
    auto take = [&](size_t bytes) { size_t r = off; off += (bytes + 255) & ~(size_t)255; return r; };
    const size_t N = NNODES, M = NM;
    int*   counts = (int*)(w + take(N * 4));
    int*   cursor = (int*)(w + take(N * 4));
    size_t zero_span = off;                              // counts+cursor contiguous
    int*   offs   = (int*)(w + take((N + 1) * 4));
    int*   csr    = (int*)(w + take((size_t)ETOT * 4));
    float* xw0    = (float*)(w + take(M * 64 * 4));
    float* xres0  = (float*)(w + take(M * 64 * 4));
    float* als0   = (float*)(w + take(M * 2 * 4));
    float* ald0   = (float*)(w + take(M * 2 * 4));
    float* xw1    = (float*)(w + take(M * 32 * 4));
    float* xres1  = (float*)(w + take(M * 32 * 4));
    float* als1   = (float*)(w + take(M * 4));
    float* ald1   = (float*)(w + take(M * 4));
    float* gi0    = (float*)(w + take(M * 192 * 4));   // 38.4 MB
    float* wiT0   = (float*)(w + take(32 * 192 * 4));
    float* whT0   = (float*)(w + take(64 * 192 * 4));
    float* wiT1   = (float*)(w + take(64 * 192 * 4));
    float* whT1   = (float*)(w + take(64 * 192 * 4));
    // packed blob: h0rz|h0n|i1rz|i1n|h1rz|h1n contiguous (147456 B)
    char*   blob  = w + take(147456);
    float2* h0rz  = (float2*)blob;
    float*  h0n   = (float*)(blob + 32768);
    float2* i1rz  = (float2*)(blob + 49152);
    float*  i1n   = (float*)(blob + 81920);
    float2* h1rz  = (float2*)(blob + 98304);
    float*  h1n   = (float*)(blob + 131072);

    hipMemsetAsync(w, 0, zero_span, stream);            // counts + cursor in one memset

    // fused preamble: edge count | weight transpose | GAT0 projections (independent partitions)
    k_preamble<<<CNT_BLKS + TRN_BLKS + MM0_BLKS, 256, 0, stream>>>(
        ei, counts,
        gru0_Wi, gru0_Wh, gru1_Wi, gru1_Wh,
        wiT0, whT0, wiT1, whT1,
        h0rz, h0n, i1rz, i1n, h1rz, h1n,
        x_seq, gat0_W, res0_W, gat0_as, gat0_ad, xw0, xres0, als0, ald0);

    k_scan<<<1, 1024, 0, stream>>>(counts, offs);
    k_fill<<<CNT_BLKS, 256, 0, stream>>>(ei, offs, cursor, csr);

    k_gat0_all<<<MM0_BLKS, 256, 0, stream>>>(xw0, xres0, als0, ald0, offs, csr, gat0_b,
                                             gat1_W, res1_W, gat1_as, gat1_ad,
                                             xw1, xres1, als1, ald1);
    k_gat1_all<<<MM0_BLKS, 256, 0, stream>>>(xw1, xres1, als1, ald1, offs, csr, gat1_b,
                                             wiT0, gru0_bi, gi0);

    // Recurrent chain + head: persistent-LDS variant (147456 B dyn shared)
    const int ggrid = NNODES / (GW * GNPW);   // 250
    hipError_t ae = hipFuncSetAttribute(reinterpret_cast<const void*>(k_gruhead_p),
                                        hipFuncAttributeMaxDynamicSharedMemorySize, 147456);
    if (ae == hipSuccess) {
        k_gruhead_p<<<ggrid, 512, 147456, stream>>>(gi0, (const float4*)blob,
                                                    gru0_bh, gru1_bi, gru1_bh,
                                                    fc1_W, fc1_b, fc2_W, fc2_b, out);
    } else {
        k_gruhead<<<ggrid, 512, 0, stream>>>(gi0, whT0, wiT1, whT1,
                                             gru0_bh, gru1_bi, gru1_bh,
                                             fc1_W, fc1_b, fc2_W, fc2_b, out);
    }
}

// Round 14
// 361.636 us; speedup vs baseline: 1.0922x; 1.0177x over previous
//
#include <hip/hip_runtime.h>
#include <hip/hip_bf16.h>
#include <math.h>

#define T_STEPS 5
#define NNODES  10000
#define NM      (T_STEPS * NNODES)   // 50000 node-instances (t,n)
#define F_IN    16
#define NEDGES  160000
#define ETOT    (NEDGES + NNODES)    // + self loops
#define GW      8                    // waves per block in gruhead (512 threads)
#define GNPW    5                    // nodes per wave: 8*5=40 nodes/block, 250 blocks

// grid partition for the fused preamble kernel
#define CNT_BLKS 665                 // ceil(ETOT/256)
#define TRN_BLKS 216                 // 55296/256
#define MM0_BLKS 12500               // ceil(NM/4)

// SGPR broadcast: readlane — index MUST be wave-uniform
#define RL(v, k)  __int_as_float(__builtin_amdgcn_readlane(__float_as_int(v), (k)))
#define RLI(v, k) __builtin_amdgcn_readlane((v), (k))

// ---------------- CSR scan + fill ----------------
__global__ __launch_bounds__(1024) void k_scan(const int* __restrict__ counts, int* __restrict__ offs) {
    __shared__ int ssum[1024];
    int t = threadIdx.x;
    const int chunk = (NNODES + 1023) / 1024;
    int start = t * chunk, end = min(start + chunk, NNODES);
    int s = 0;
    for (int i = start; i < end; i++) s += counts[i];
    ssum[t] = s;
    __syncthreads();
    for (int off = 1; off < 1024; off <<= 1) {
        int v = (t >= off) ? ssum[t - off] : 0;
        __syncthreads();
        ssum[t] += v;
        __syncthreads();
    }
    int excl = (t == 0) ? 0 : ssum[t - 1];
    for (int i = start; i < end; i++) { offs[i] = excl; excl += counts[i]; }
    if (t == 1023) offs[NNODES] = ssum[1023];
}

__global__ __launch_bounds__(256) void k_fill(const int* __restrict__ ei, const int* __restrict__ offs,
                                              int* __restrict__ cursor, int* __restrict__ csr) {
    int idx = blockIdx.x * 256 + threadIdx.x;
    if (idx >= ETOT) return;
    int src, dst;
    if (idx < NEDGES) { src = ei[idx]; dst = ei[NEDGES + idx]; }
    else              { src = dst = idx - NEDGES; }
    int p = atomicAdd(&cursor[dst], 1);
    csr[offs[dst] + p] = src;
}

// ---------------- fused preamble: edge count | weight transpose | GAT0 projections ----------------
// blob layout (147456 B): h0rz@0 | h0n@32768 | i1rz@49152 | i1n@81920 | h1rz@98304 | h1n@131072
__global__ __launch_bounds__(256) void k_preamble(const int* __restrict__ ei, int* __restrict__ counts,
                                                  const float* __restrict__ Wi0, const float* __restrict__ Wh0,
                                                  const float* __restrict__ Wi1, const float* __restrict__ Wh1,
                                                  float* __restrict__ WiT0, float* __restrict__ WhT0,
                                                  float* __restrict__ WiT1, float* __restrict__ WhT1,
                                                  float2* __restrict__ h0rz, float* __restrict__ h0n,
                                                  float2* __restrict__ i1rz, float* __restrict__ i1n,
                                                  float2* __restrict__ h1rz, float* __restrict__ h1n,
                                                  const float* __restrict__ x,     // [5N,16]
                                                  const float* __restrict__ W,    // [16,64]
                                                  const float* __restrict__ Wres, // [16,64]
                                                  const float* __restrict__ asrc, const float* __restrict__ adst,
                                                  float* __restrict__ xw, float* __restrict__ xres,
                                                  float* __restrict__ als, float* __restrict__ ald) {
    int b = blockIdx.x;
    if (b < CNT_BLKS) {
        int idx = b * 256 + threadIdx.x;
        if (idx >= ETOT) return;
        int dst = (idx < NEDGES) ? ei[NEDGES + idx] : (idx - NEDGES);
        atomicAdd(&counts[dst], 1);
        return;
    }
    if (b < CNT_BLKS + TRN_BLKS) {
        int idx = (b - CNT_BLKS) * 256 + threadIdx.x;
        if (idx < 6144)  { int k = idx / 192, r = idx % 192; WiT0[idx] = Wi0[r * 32 + k]; return; }
        idx -= 6144;
        if (idx < 12288) { int k = idx / 192, r = idx % 192; WhT0[idx] = Wh0[r * 64 + k]; return; }
        idx -= 12288;
        if (idx < 12288) { int k = idx / 192, r = idx % 192; WiT1[idx] = Wi1[r * 64 + k]; return; }
        idx -= 12288;
        if (idx < 12288) { int k = idx / 192, r = idx % 192; WhT1[idx] = Wh1[r * 64 + k]; return; }
        idx -= 12288;
        if (idx < 4096) { int k = idx >> 6, c = idx & 63;
                          h0rz[idx] = make_float2(Wh0[c * 64 + k], Wh0[(64 + c) * 64 + k]);
                          h0n[idx]  = Wh0[(128 + c) * 64 + k]; return; }
        idx -= 4096;
        if (idx < 4096) { int k = idx >> 6, c = idx & 63;
                          i1rz[idx] = make_float2(Wi1[c * 64 + k], Wi1[(64 + c) * 64 + k]);
                          i1n[idx]  = Wi1[(128 + c) * 64 + k]; return; }
        idx -= 4096;
        if (idx < 4096) { int k = idx >> 6, c = idx & 63;
                          h1rz[idx] = make_float2(Wh1[c * 64 + k], Wh1[(64 + c) * 64 + k]);
                          h1n[idx]  = Wh1[(128 + c) * 64 + k]; }
        return;
    }
    // ---- GAT0 projections (all timesteps) ----
    int wave = threadIdx.x >> 6, lane = threadIdx.x & 63;
    int m = (b - CNT_BLKS - TRN_BLKS) * 4 + wave;
    if (m >= NM) return;
    const float* xr = x + (size_t)m * F_IN;
    float xreg[F_IN];
#pragma unroll
    for (int k = 0; k < F_IN; k++) xreg[k] = xr[k];
    float acc = 0.f, accr = 0.f;
#pragma unroll
    for (int k = 0; k < F_IN; k++) {
        acc  += xreg[k] * W[k * 64 + lane];
        accr += xreg[k] * Wres[k * 64 + lane];
    }
    xw[(size_t)m * 64 + lane]   = acc;
    xres[(size_t)m * 64 + lane] = accr;
    float ps = acc * asrc[lane], pd = acc * adst[lane];
    for (int off = 16; off; off >>= 1) {
        ps += __shfl_down(ps, off, 32);
        pd += __shfl_down(pd, off, 32);
    }
    if ((lane & 31) == 0) {
        int h = lane >> 5;
        als[m * 2 + h] = ps;
        ald[m * 2 + h] = pd;
    }
}

// ---------------- fused GAT0 gather + ELU + residual + GAT1 projection, ALL timesteps ----------------
__global__ __launch_bounds__(256) void k_gat0_all(const float* __restrict__ xw,   // [5N,64]
                                                  const float* __restrict__ xres, // [5N,64]
                                                  const float* __restrict__ als,  // [5N,2]
                                                  const float* __restrict__ ald,  // [5N,2]
                                                  const int* __restrict__ offs, const int* __restrict__ csr,
                                                  const float* __restrict__ b,    // [64]
                                                  const float* __restrict__ W1,   // [64,32]
                                                  const float* __restrict__ Wres1,// [64,32]
                                                  const float* __restrict__ as1,  // [32]
                                                  const float* __restrict__ ad1v, // [32]
                                                  float* __restrict__ xw1, float* __restrict__ xres1,
                                                  float* __restrict__ als1, float* __restrict__ ald1) {
    int wave = threadIdx.x >> 6, lane = threadIdx.x & 63;
    int m = blockIdx.x * 4 + wave;
    if (m >= NM) return;
    int t = m / NNODES;
    int node = m - t * NNODES;
    int base = t * NNODES;
    int beg = offs[node], end = offs[node + 1];
    int deg = end - beg;
    float ad0 = ald[m * 2 + 0], ad1 = ald[m * 2 + 1];
    float acc;
    if (deg <= 64) {
        int s = 0; float e0 = -INFINITY, e1 = -INFINITY;
        if (lane < deg) {
            s = base + csr[beg + lane];
            e0 = als[s * 2 + 0] + ad0; e0 = e0 > 0.f ? e0 : 0.2f * e0;
            e1 = als[s * 2 + 1] + ad1; e1 = e1 > 0.f ? e1 : 0.2f * e1;
        }
        float m0 = e0, m1 = e1;
        for (int o = 32; o; o >>= 1) {
            m0 = fmaxf(m0, __shfl_xor(m0, o));
            m1 = fmaxf(m1, __shfl_xor(m1, o));
        }
        float ex0 = (lane < deg) ? __expf(e0 - m0) : 0.f;
        float ex1 = (lane < deg) ? __expf(e1 - m1) : 0.f;
        float d0 = ex0, d1 = ex1;
        for (int o = 32; o; o >>= 1) {
            d0 += __shfl_xor(d0, o);
            d1 += __shfl_xor(d1, o);
        }
        ex0 *= 1.f / (d0 + 1e-16f);
        ex1 *= 1.f / (d1 + 1e-16f);
        // aggregation: 8 independent gathers in flight per iteration (all RL indices uniform)
        float a0 = 0.f, a1 = 0.f, a2 = 0.f, a3 = 0.f;
        int i = 0;
        for (; i + 8 <= deg; i += 8) {
            int   s0 = RLI(s, i),    s1 = RLI(s, i+1), s2 = RLI(s, i+2), s3 = RLI(s, i+3);
            int   s4 = RLI(s, i+4),  s5 = RLI(s, i+5), s6 = RLI(s, i+6), s7 = RLI(s, i+7);
            float x0 = xw[(size_t)s0 * 64 + lane];
            float x1 = xw[(size_t)s1 * 64 + lane];
            float x2 = xw[(size_t)s2 * 64 + lane];
            float x3 = xw[(size_t)s3 * 64 + lane];
            float x4 = xw[(size_t)s4 * 64 + lane];
            float x5 = xw[(size_t)s5 * 64 + lane];
            float x6 = xw[(size_t)s6 * 64 + lane];
            float x7 = xw[(size_t)s7 * 64 + lane];
            float u0 = (lane < 32) ? RL(ex0, i)   : RL(ex1, i);
            float u1 = (lane < 32) ? RL(ex0, i+1) : RL(ex1, i+1);
            float u2 = (lane < 32) ? RL(ex0, i+2) : RL(ex1, i+2);
            float u3 = (lane < 32) ? RL(ex0, i+3) : RL(ex1, i+3);
            float u4 = (lane < 32) ? RL(ex0, i+4) : RL(ex1, i+4);
            float u5 = (lane < 32) ? RL(ex0, i+5) : RL(ex1, i+5);
            float u6 = (lane < 32) ? RL(ex0, i+6) : RL(ex1, i+6);
            float u7 = (lane < 32) ? RL(ex0, i+7) : RL(ex1, i+7);
            a0 += u0 * x0 + u4 * x4;
            a1 += u1 * x1 + u5 * x5;
            a2 += u2 * x2 + u6 * x6;
            a3 += u3 * x3 + u7 * x7;
        }
        for (; i < deg; i++) {
            int s0 = RLI(s, i);
            float u = (lane < 32) ? RL(ex0, i) : RL(ex1, i);
            a0 += u * xw[(size_t)s0 * 64 + lane];
        }
        acc = (a0 + a1) + (a2 + a3);
    } else {
        float m0 = -INFINITY, m1 = -INFINITY;
        for (int i = beg + lane; i < end; i += 64) {
            int s = base + csr[i];
            float e0 = als[s * 2 + 0] + ad0; e0 = e0 > 0.f ? e0 : 0.2f * e0;
            float e1 = als[s * 2 + 1] + ad1; e1 = e1 > 0.f ? e1 : 0.2f * e1;
            m0 = fmaxf(m0, e0); m1 = fmaxf(m1, e1);
        }
        for (int o = 32; o; o >>= 1) {
            m0 = fmaxf(m0, __shfl_xor(m0, o));
            m1 = fmaxf(m1, __shfl_xor(m1, o));
        }
        float d0 = 0.f, d1 = 0.f;
        for (int i = beg + lane; i < end; i += 64) {
            int s = base + csr[i];
            float e0 = als[s * 2 + 0] + ad0; e0 = e0 > 0.f ? e0 : 0.2f * e0;
            float e1 = als[s * 2 + 1] + ad1; e1 = e1 > 0.f ? e1 : 0.2f * e1;
            d0 += __expf(e0 - m0); d1 += __expf(e1 - m1);
        }
        for (int o = 32; o; o >>= 1) { d0 += __shfl_xor(d0, o); d1 += __shfl_xor(d1, o); }
        float inv0 = 1.f / (d0 + 1e-16f), inv1 = 1.f / (d1 + 1e-16f);
        acc = 0.f;
        for (int i = beg; i < end; i++) {
            int s = base + csr[i];
            float e, wgt;
            if (lane < 32) { e = als[s * 2 + 0] + ad0; e = e > 0.f ? e : 0.2f * e; wgt = __expf(e - m0) * inv0; }
            else           { e = als[s * 2 + 1] + ad1; e = e > 0.f ? e : 0.2f * e; wgt = __expf(e - m1) * inv1; }
            acc += wgt * xw[(size_t)s * 64 + lane];
        }
    }
    float x1v = acc + b[lane];
    x1v = x1v > 0.f ? x1v : expm1f(x1v);
    x1v += xres[(size_t)m * 64 + lane];
    // GAT1 projection: readlane broadcasts
    int j = lane & 31;
    const float* Wp = (lane < 32) ? W1 : Wres1;
    float pacc = 0.f;
#pragma unroll
    for (int k = 0; k < 64; k++) {
        float xv = RL(x1v, k);
        pacc += xv * Wp[k * 32 + j];
    }
    if (lane < 32) xw1[(size_t)m * 32 + j]   = pacc;
    else           xres1[(size_t)m * 32 + j] = pacc;
    float ps = (lane < 32) ? pacc * as1[j]  : 0.f;
    float pd = (lane < 32) ? pacc * ad1v[j] : 0.f;
    for (int o = 16; o; o >>= 1) {
        ps += __shfl_down(ps, o, 32);
        pd += __shfl_down(pd, o, 32);
    }
    if (lane == 0) { als1[m] = ps; ald1[m] = pd; }
}

// ---------------- GAT1 gather -> x2 -> fused GRU0 input projection gi0, ALL timesteps ----------------
__global__ __launch_bounds__(256) void k_gat1_all(const float* __restrict__ xw1,   // [5N,32]
                                                  const float* __restrict__ xres1, // [5N,32]
                                                  const float* __restrict__ als1,  // [5N]
                                                  const float* __restrict__ ald1,  // [5N]
                                                  const int* __restrict__ offs, const int* __restrict__ csr,
                                                  const float* __restrict__ b,     // [32]
                                                  const float* __restrict__ WiT0,  // [32,192] k-major
                                                  const float* __restrict__ bi0,   // [192]
                                                  float* __restrict__ gi0) {
    int wave = threadIdx.x >> 6, lane = threadIdx.x & 63;
    int m = blockIdx.x * 4 + wave;
    if (m >= NM) return;
    int t = m / NNODES;
    int node = m - t * NNODES;
    int base = t * NNODES;
    int beg = offs[node], end = offs[node + 1];
    int deg = end - beg;
    float adv = ald1[m];
    int ch = lane & 31, half = lane >> 5;
    float aggr;
    if (deg <= 64) {
        int s = 0; float e = -INFINITY;
        if (lane < deg) {
            s = base + csr[beg + lane];
            e = als1[s] + adv; e = e > 0.f ? e : 0.2f * e;
        }
        float mx = e;
        for (int o = 32; o; o >>= 1) mx = fmaxf(mx, __shfl_xor(mx, o));
        float ex = (lane < deg) ? __expf(e - mx) : 0.f;
        float d = ex;
        for (int o = 32; o; o >>= 1) d += __shfl_xor(d, o);
        ex *= 1.f / (d + 1e-16f);
        // 8 edges per iteration: uniform readlanes for all 8, per-half SELECT (legal)
        float acc0 = 0.f, acc1 = 0.f;
        int i = 0;
        for (; i + 8 <= deg; i += 8) {
            int   e0 = RLI(s, i),   o0 = RLI(s, i+1);
            int   e1 = RLI(s, i+2), o1 = RLI(s, i+3);
            int   e2 = RLI(s, i+4), o2 = RLI(s, i+5);
            int   e3 = RLI(s, i+6), o3 = RLI(s, i+7);
            int   sa0 = half ? o0 : e0, sa1 = half ? o1 : e1;
            int   sa2 = half ? o2 : e2, sa3 = half ? o3 : e3;
            float xa0 = xw1[(size_t)sa0 * 32 + ch];
            float xa1 = xw1[(size_t)sa1 * 32 + ch];
            float xa2 = xw1[(size_t)sa2 * 32 + ch];
            float xa3 = xw1[(size_t)sa3 * 32 + ch];
            float we0 = RL(ex, i),   wo0 = RL(ex, i+1);
            float we1 = RL(ex, i+2), wo1 = RL(ex, i+3);
            float we2 = RL(ex, i+4), wo2 = RL(ex, i+5);
            float we3 = RL(ex, i+6), wo3 = RL(ex, i+7);
            float wa0 = half ? wo0 : we0, wa1 = half ? wo1 : we1;
            float wa2 = half ? wo2 : we2, wa3 = half ? wo3 : we3;
            acc0 += wa0 * xa0 + wa2 * xa2;
            acc1 += wa1 * xa1 + wa3 * xa3;
        }
        for (; i < deg; i += 2) {
            int i2 = (i + 1 < deg) ? i + 1 : i;
            int   sa = RLI(s, i),  sb = RLI(s, i2);
            float wa = RL(ex, i),  wb = RL(ex, i2);
            if (i + 1 >= deg) wb = 0.f;
            int   sm = half ? sb : sa;
            float wm = half ? wb : wa;
            acc0 += wm * xw1[(size_t)sm * 32 + ch];
        }
        float acc = acc0 + acc1;
        acc += __shfl_xor(acc, 32);
        aggr = acc;
    } else {
        float mx = -INFINITY;
        for (int i = beg + lane; i < end; i += 64) {
            float e = als1[base + csr[i]] + adv; e = e > 0.f ? e : 0.2f * e;
            mx = fmaxf(mx, e);
        }
        for (int o = 32; o; o >>= 1) mx = fmaxf(mx, __shfl_xor(mx, o));
        float d = 0.f;
        for (int i = beg + lane; i < end; i += 64) {
            float e = als1[base + csr[i]] + adv; e = e > 0.f ? e : 0.2f * e;
            d += __expf(e - mx);
        }
        for (int o = 32; o; o >>= 1) d += __shfl_xor(d, o);
        float inv = 1.f / (d + 1e-16f);
        float acc = 0.f;
        for (int i = beg; i < end; i++) {
            int s = base + csr[i];
            float e = als1[s] + adv; e = e > 0.f ? e : 0.2f * e;
            float wgt = __expf(e - mx) * inv;
            acc += wgt * xw1[(size_t)s * 32 + ch];
        }
        aggr = acc;
    }
    // x2 value (identical on both wave halves: ch = lane&31)
    float v = aggr + b[ch];
    v = v > 0.f ? v : expm1f(v);
    float x2v = v + xres1[(size_t)m * 32 + ch];
    // gi0 = x2 @ WiT0 + bi0 — k-outer: one RL serves three output blocks (32 RLs not 96)
    float p0 = bi0[lane], p1 = bi0[64 + lane], p2 = bi0[128 + lane];
#pragma unroll 8
    for (int k = 0; k < 32; k++) {
        float xv = RL(x2v, k);
        p0 += xv * WiT0[k * 192 + lane];
        p1 += xv * WiT0[k * 192 + 64 + lane];
        p2 += xv * WiT0[k * 192 + 128 + lane];
    }
    gi0[(size_t)m * 192 + lane]       = p0;
    gi0[(size_t)m * 192 + 64 + lane]  = p1;
    gi0[(size_t)m * 192 + 128 + lane] = p2;
}

// ---------------- persistent-LDS GRU chain + head: RL broadcasts, 2 DS/k, gi0 software pipeline ----------------
__global__ __launch_bounds__(512) void k_gruhead_p(const float* __restrict__ gi0,    // [5N,192]
                                                   const float4* __restrict__ wblob, // packed weights, 147456 B
                                                   const float* __restrict__ bh0,
                                                   const float* __restrict__ bi1, const float* __restrict__ bh1,
                                                   const float* __restrict__ fc1W, const float* __restrict__ fc1b,
                                                   const float* __restrict__ fc2W, const float* __restrict__ fc2b,
                                                   float* __restrict__ out) {
    extern __shared__ char ldsraw[];                // 147456 B
    float2* Lh0rz = (float2*)ldsraw;                // 32768
    float*  Lh0n  = (float*)(ldsraw + 32768);       // 16384
    float2* Li1rz = (float2*)(ldsraw + 49152);
    float*  Li1n  = (float*)(ldsraw + 81920);
    float2* Lh1rz = (float2*)(ldsraw + 98304);
    float*  Lh1n  = (float*)(ldsraw + 131072);
    int tid = threadIdx.x, wave = tid >> 6, lane = tid & 63;
    int node0 = (blockIdx.x * GW + wave) * GNPW;    // 250*8*5 = 10000 exactly

    {
        float4* D = (float4*)ldsraw;
#pragma unroll
        for (int i = 0; i < 18; i++) D[tid + i * 512] = wblob[tid + i * 512];
    }

    // prefetch t=0 gi0 while LDS staging drains
    float pr[GNPW], pz[GNPW], pn[GNPW];
#pragma unroll
    for (int n = 0; n < GNPW; n++) {
        size_t gb = ((size_t)node0 + n) * 192;
        pr[n] = gi0[gb + lane];
        pz[n] = gi0[gb + 64 + lane];
        pn[n] = gi0[gb + 128 + lane];
    }
    __syncthreads();                                // the only barrier

    float bhr0 = bh0[lane], bhz0 = bh0[64 + lane], bhn0 = bh0[128 + lane];
    float bir1 = bi1[lane] + bh1[lane];
    float biz1 = bi1[64 + lane] + bh1[64 + lane];
    float bin1 = bi1[128 + lane], bhn1 = bh1[128 + lane];

    float h0[GNPW] = {0.f, 0.f, 0.f, 0.f, 0.f};
    float h1[GNPW] = {0.f, 0.f, 0.f, 0.f, 0.f};

    for (int t = 0; t < T_STEPS; t++) {
        float gr[GNPW], gz[GNPW], gin[GNPW], ghn[GNPW];
#pragma unroll
        for (int n = 0; n < GNPW; n++) {
            gr[n]  = pr[n] + bhr0;
            gz[n]  = pz[n] + bhz0;
            gin[n] = pn[n];
            ghn[n] = bhn0;
        }
        // issue prefetch for t+1 now — hidden under the k-loops below
        if (t + 1 < T_STEPS) {
            size_t gb1 = ((size_t)(t + 1) * NNODES + node0) * 192;
#pragma unroll
            for (int n = 0; n < GNPW; n++) {
                pr[n] = gi0[gb1 + n * 192 + lane];
                pz[n] = gi0[gb1 + n * 192 + 64 + lane];
                pn[n] = gi0[gb1 + n * 192 + 128 + lane];
            }
        }
        // GRU0 h-part (K=64): 2 DS reads per k
#pragma unroll 8
        for (int k = 0; k < 64; k++) {
            float2 wrz = Lh0rz[k * 64 + lane];
            float  wn  = Lh0n[k * 64 + lane];
#pragma unroll
            for (int n = 0; n < GNPW; n++) {
                float hv = RL(h0[n], k);
                gr[n] += hv * wrz.x; gz[n] += hv * wrz.y; ghn[n] += hv * wn;
            }
        }
#pragma unroll
        for (int n = 0; n < GNPW; n++) {
            float r = 1.f / (1.f + __expf(-gr[n]));
            float z = 1.f / (1.f + __expf(-gz[n]));
            float nn = tanhf(gin[n] + r * ghn[n]);
            h0[n] = (1.f - z) * nn + z * h0[n];
        }

        // GRU1 x-pass (x = h0 new)
#pragma unroll
        for (int n = 0; n < GNPW; n++) { gr[n] = bir1; gz[n] = biz1; gin[n] = bin1; }
#pragma unroll 8
        for (int k = 0; k < 64; k++) {
            float2 wrz = Li1rz[k * 64 + lane];
            float  wn  = Li1n[k * 64 + lane];
#pragma unroll
            for (int n = 0; n < GNPW; n++) {
                float xv = RL(h0[n], k);
                gr[n] += xv * wrz.x; gz[n] += xv * wrz.y; gin[n] += xv * wn;
            }
        }
        // GRU1 h-pass
#pragma unroll
        for (int n = 0; n < GNPW; n++) ghn[n] = bhn1;
#pragma unroll 8
        for (int k = 0; k < 64; k++) {
            float2 wrz = Lh1rz[k * 64 + lane];
            float  wn  = Lh1n[k * 64 + lane];
#pragma unroll
            for (int n = 0; n < GNPW; n++) {
                float hv = RL(h1[n], k);
                gr[n] += hv * wrz.x; gz[n] += hv * wrz.y; ghn[n] += hv * wn;
            }
        }
#pragma unroll
        for (int n = 0; n < GNPW; n++) {
            float r = 1.f / (1.f + __expf(-gr[n]));
            float z = 1.f / (1.f + __expf(-gz[n]));
            float nn = tanhf(gin[n] + r * ghn[n]);
            h1[n] = (1.f - z) * nn + z * h1[n];
        }
    }

    // MLP head
    int j = lane & 31, half = lane >> 5;
#pragma unroll
    for (int p = 0; p < 3; p++) {
        int ne = 2 * p;
        int no = (2 * p + 1 < GNPW) ? 2 * p + 1 : 2 * p;
        float a = fc1b[j];
#pragma unroll
        for (int k = 0; k < 64; k++) {
            float he = RL(h1[ne], k);
            float ho = RL(h1[no], k);
            a += (half ? ho : he) * fc1W[k * 32 + j];
        }
        a = fmaxf(a, 0.f);
        float v = a * fc2W[j];
        for (int o = 16; o; o >>= 1) v += __shfl_down(v, o, 32);
        if ((lane & 31) == 0 && 2 * p + half < GNPW) out[node0 + 2 * p + half] = v + fc2b[0];
    }
}

// ---------------- fallback: per-phase LDS staging (49KB static), flat weights ----------------
__global__ __launch_bounds__(512) void k_gruhead(const float* __restrict__ gi0,
                                                 const float* __restrict__ WhT0,
                                                 const float* __restrict__ WiT1,
                                                 const float* __restrict__ WhT1,
                                                 const float* __restrict__ bh0,
                                                 const float* __restrict__ bi1, const float* __restrict__ bh1,
                                                 const float* __restrict__ fc1W, const float* __restrict__ fc1b,
                                                 const float* __restrict__ fc2W, const float* __restrict__ fc2b,
                                                 float* __restrict__ out) {
    __shared__ float lw[64 * 192];
    int tid = threadIdx.x;
    int wave = tid >> 6, lane = tid & 63;
    int node0 = (blockIdx.x * GW + wave) * GNPW;

    float bhr0 = bh0[lane], bhz0 = bh0[64 + lane], bhn0 = bh0[128 + lane];
    float bir1 = bi1[lane] + bh1[lane];
    float biz1 = bi1[64 + lane] + bh1[64 + lane];
    float bin1 = bi1[128 + lane], bhn1 = bh1[128 + lane];

    float h0[GNPW] = {0.f, 0.f, 0.f, 0.f, 0.f};
    float h1[GNPW] = {0.f, 0.f, 0.f, 0.f, 0.f};

    auto stage = [&](const float* __restrict__ src) {
        __syncthreads();
        const float4* s4 = (const float4*)src;
        float4* d4 = (float4*)lw;
#pragma unroll
        for (int i = 0; i < 6; i++) d4[tid + i * 512] = s4[tid + i * 512];
        __syncthreads();
    };

    for (int t = 0; t < T_STEPS; t++) {
        float gr[GNPW], gz[GNPW], gin[GNPW], ghn[GNPW];
        size_t gb = ((size_t)t * NNODES + node0) * 192;
#pragma unroll
        for (int n = 0; n < GNPW; n++) {
            gr[n]  = gi0[gb + n * 192 + lane] + bhr0;
            gz[n]  = gi0[gb + n * 192 + 64 + lane] + bhz0;
            gin[n] = gi0[gb + n * 192 + 128 + lane];
            ghn[n] = bhn0;
        }
        stage(WhT0);
#pragma unroll 4
        for (int k = 0; k < 64; k++) {
            float wr = lw[k * 192 + lane];
            float wz = lw[k * 192 + 64 + lane];
            float wn = lw[k * 192 + 128 + lane];
#pragma unroll
            for (int n = 0; n < GNPW; n++) {
                float hv = RL(h0[n], k);
                gr[n] += hv * wr; gz[n] += hv * wz; ghn[n] += hv * wn;
            }
        }
#pragma unroll
        for (int n = 0; n < GNPW; n++) {
            float r = 1.f / (1.f + __expf(-gr[n]));
            float z = 1.f / (1.f + __expf(-gz[n]));
            float nn = tanhf(gin[n] + r * ghn[n]);
            h0[n] = (1.f - z) * nn + z * h0[n];
        }
#pragma unroll
        for (int n = 0; n < GNPW; n++) { gr[n] = bir1; gz[n] = biz1; gin[n] = bin1; }
        stage(WiT1);
#pragma unroll 4
        for (int k = 0; k < 64; k++) {
            float wir = lw[k * 192 + lane];
            float wiz = lw[k * 192 + 64 + lane];
            float win = lw[k * 192 + 128 + lane];
#pragma unroll
            for (int n = 0; n < GNPW; n++) {
                float xv = RL(h0[n], k);
                gr[n] += xv * wir; gz[n] += xv * wiz; gin[n] += xv * win;
            }
        }
#pragma unroll
        for (int n = 0; n < GNPW; n++) ghn[n] = bhn1;
        stage(WhT1);
#pragma unroll 4
        for (int k = 0; k < 64; k++) {
            float whr = lw[k * 192 + lane];
            float whz = lw[k * 192 + 64 + lane];
            float whn = lw[k * 192 + 128 + lane];
#pragma unroll
            for (int n = 0; n < GNPW; n++) {
                float hv = RL(h1[n], k);
                gr[n] += hv * whr; gz[n] += hv * whz; ghn[n] += hv * whn;
            }
        }
#pragma unroll
        for (int n = 0; n < GNPW; n++) {
            float r = 1.f / (1.f + __expf(-gr[n]));
            float z = 1.f / (1.f + __expf(-gz[n]));
            float nn = tanhf(gin[n] + r * ghn[n]);
            h1[n] = (1.f - z) * nn + z * h1[n];
        }
    }

    int j = lane & 31, half = lane >> 5;
#pragma unroll
    for (int p = 0; p < 3; p++) {
        int ne = 2 * p;
        int no = (2 * p + 1 < GNPW) ? 2 * p + 1 : 2 * p;
        float a = fc1b[j];
#pragma unroll
        for (int k = 0; k < 64; k++) {
            float he = RL(h1[ne], k);
            float ho = RL(h1[no], k);
            a += (half ? ho : he) * fc1W[k * 32 + j];
        }
        a = fmaxf(a, 0.f);
        float v = a * fc2W[j];
        for (int o = 16; o; o >>= 1) v += __shfl_down(v, o, 32);
        if ((lane & 31) == 0 && 2 * p + half < GNPW) out[node0 + 2 * p + half] = v + fc2b[0];
    }
}

extern "C" void kernel_launch(void* const* d_in, const int* in_sizes, int n_in,
                              void* d_out, int out_size, void* d_ws, size_t ws_size,
                              hipStream_t stream) {
    const float* x_seq   = (const float*)d_in[0];
    const int*   ei      = (const int*)d_in[1];
    const float* gat0_W  = (const float*)d_in[2];
    const float* gat0_as = (const float*)d_in[3];
    const float* gat0_ad = (const float*)d_in[4];
    const float* gat0_b  = (const float*)d_in[5];
    const float* res0_W  = (const float*)d_in[6];
    const float* gat1_W  = (const float*)d_in[7];
    const float* gat1_as = (const float*)d_in[8];
    const float* gat1_ad = (const float*)d_in[9];
    const float* gat1_b  = (const float*)d_in[10];
    const float* res1_W  = (const float*)d_in[11];
    const float* gru0_Wi = (const float*)d_in[12];
    const float* gru0_Wh = (const float*)d_in[13];
    const float* gru0_bi = (const float*)d_in[14];
    const float* gru0_bh = (const float*)d_in[15];
    const float* gru1_Wi = (const float*)d_in[16];
    const float* gru1_Wh = (const float*)d_in[17];
    const float* gru1_bi = (const float*)d_in[18];
    const float* gru1_bh = (const float*)d_in[19];
    const float* fc1_W   = (const float*)d_in[20];
    const float* fc1_b   = (const float*)d_in[21];
    const float* fc2_W   = (const float*)d_in[22];
    const float* fc2_b   = (const float*)d_in[23];
    float* out = (float*)d_out;

    char* w = (char*)d_ws;
    size_t off = 0;
    auto take = [&](size_t bytes) { size_t r = off; off += (bytes + 255) & ~(size_t)255; return r; };
    const size_t N = NNODES, M = NM;
    int*   counts = (int*)(w + take(N * 4));
    int*   cursor = (int*)(w + take(N * 4));
    size_t zero_span = off;                              // counts+cursor contiguous
    int*   offs   = (int*)(w + take((N + 1) * 4));
    int*   csr    = (int*)(w + take((size_t)ETOT * 4));
    float* xw0    = (float*)(w + take(M * 64 * 4));
    float* xres0  = (float*)(w + take(M * 64 * 4));
    float* als0   = (float*)(w + take(M * 2 * 4));
    float* ald0   = (float*)(w + take(M * 2 * 4));
    float* xw1    = (float*)(w + take(M * 32 * 4));
    float* xres1  = (float*)(w + take(M * 32 * 4));
    float* als1   = (float*)(w + take(M * 4));
    float* ald1   = (float*)(w + take(M * 4));
    float* gi0    = (float*)(w + take(M * 192 * 4));   // 38.4 MB
    float* wiT0   = (float*)(w + take(32 * 192 * 4));
    float* whT0   = (float*)(w + take(64 * 192 * 4));
    float* wiT1   = (float*)(w + take(64 * 192 * 4));
    float* whT1   = (float*)(w + take(64 * 192 * 4));
    // packed blob: h0rz|h0n|i1rz|i1n|h1rz|h1n contiguous (147456 B)
    char*   blob  = w + take(147456);
    float2* h0rz  = (float2*)blob;
    float*  h0n   = (float*)(blob + 32768);
    float2* i1rz  = (float2*)(blob + 49152);
    float*  i1n   = (float*)(blob + 81920);
    float2* h1rz  = (float2*)(blob + 98304);
    float*  h1n   = (float*)(blob + 131072);

    hipMemsetAsync(w, 0, zero_span, stream);            // counts + cursor in one memset

    // fused preamble: edge count | weight transpose | GAT0 projections (independent partitions)
    k_preamble<<<CNT_BLKS + TRN_BLKS + MM0_BLKS, 256, 0, stream>>>(
        ei, counts,
        gru0_Wi, gru0_Wh, gru1_Wi, gru1_Wh,
        wiT0, whT0, wiT1, whT1,
        h0rz, h0n, i1rz, i1n, h1rz, h1n,
        x_seq, gat0_W, res0_W, gat0_as, gat0_ad, xw0, xres0, als0, ald0);

    k_scan<<<1, 1024, 0, stream>>>(counts, offs);
    k_fill<<<CNT_BLKS, 256, 0, stream>>>(ei, offs, cursor, csr);

    k_gat0_all<<<MM0_BLKS, 256, 0, stream>>>(xw0, xres0, als0, ald0, offs, csr, gat0_b,
                                             gat1_W, res1_W, gat1_as, gat1_ad,
                                             xw1, xres1, als1, ald1);
    k_gat1_all<<<MM0_BLKS, 256, 0, stream>>>(xw1, xres1, als1, ald1, offs, csr, gat1_b,
                                             wiT0, gru0_bi, gi0);

    // Recurrent chain + head: persistent-LDS variant (147456 B dyn shared)
    const int ggrid = NNODES / (GW * GNPW);   // 250
    hipError_t ae = hipFuncSetAttribute(reinterpret_cast<const void*>(k_gruhead_p),
                                        hipFuncAttributeMaxDynamicSharedMemorySize, 147456);
    if (ae == hipSuccess) {
        k_gruhead_p<<<ggrid, 512, 147456, stream>>>(gi0, (const float4*)blob,
                                                    gru0_bh, gru1_bi, gru1_bh,
                                                    fc1_W, fc1_b, fc2_W, fc2_b, out);
    } else {
        k_gruhead<<<ggrid, 512, 0, stream>>>(gi0, whT0, wiT1, whT1,
                                             gru0_bh, gru1_bi, gru1_bh,
                                             fc1_W, fc1_b, fc2_W, fc2_b, out);
    }
}

// Round 15
// 356.998 us; speedup vs baseline: 1.1064x; 1.0130x over previous
//
#include <hip/hip_runtime.h>
#include <hip/hip_bf16.h>
#include <math.h>

#define T_STEPS 5
#define NNODES  10000
#define NM      (T_STEPS * NNODES)   // 50000 node-instances (t,n)
#define F_IN    16
#define NEDGES  160000
#define ETOT    (NEDGES + NNODES)    // + self loops
#define GW      8                    // waves per block in gruhead (512 threads)
#define GNPW    5                    // nodes per wave: 8*5=40 nodes/block, 250 blocks

// grid partition for the fused preamble kernel
#define CNT_BLKS 665                 // ceil(ETOT/256)
#define TRN_BLKS 216                 // 55296/256
#define MM0_BLKS 12500               // ceil(NM/4)

// SGPR broadcast: readlane — index MUST be wave-uniform
#define RL(v, k)  __int_as_float(__builtin_amdgcn_readlane(__float_as_int(v), (k)))
#define RLI(v, k) __builtin_amdgcn_readlane((v), (k))

// ---------------- CSR scan (LDS-staged, coalesced global access) + fill ----------------
__global__ __launch_bounds__(1024) void k_scan(const int* __restrict__ counts, int* __restrict__ offs) {
    __shared__ int sc[NNODES];       // 40000 B
    __shared__ int ssum[1024];
    int t = threadIdx.x;
    // coalesced load counts -> LDS
    for (int i = t; i < NNODES; i += 1024) sc[i] = counts[i];
    __syncthreads();
    const int chunk = (NNODES + 1023) / 1024;   // 10
    int start = t * chunk, end = min(start + chunk, NNODES);
    int s = 0;
    for (int i = start; i < end; i++) s += sc[i];
    ssum[t] = s;
    __syncthreads();
    for (int off = 1; off < 1024; off <<= 1) {
        int v = (t >= off) ? ssum[t - off] : 0;
        __syncthreads();
        ssum[t] += v;
        __syncthreads();
    }
    int excl = (t == 0) ? 0 : ssum[t - 1];
    // per-chunk exclusive prefix into LDS (overwrite sc in place: read then write per element)
    for (int i = start; i < end; i++) { int c = sc[i]; sc[i] = excl; excl += c; }
    __syncthreads();
    // coalesced store offs
    for (int i = t; i < NNODES; i += 1024) offs[i] = sc[i];
    if (t == 1023) offs[NNODES] = ssum[1023];
}

__global__ __launch_bounds__(256) void k_fill(const int* __restrict__ ei, const int* __restrict__ offs,
                                              int* __restrict__ cursor, int* __restrict__ csr) {
    int idx = blockIdx.x * 256 + threadIdx.x;
    if (idx >= ETOT) return;
    int src, dst;
    if (idx < NEDGES) { src = ei[idx]; dst = ei[NEDGES + idx]; }
    else              { src = dst = idx - NEDGES; }
    int p = atomicAdd(&cursor[dst], 1);
    csr[offs[dst] + p] = src;
}

// ---------------- fused preamble: edge count | weight transpose | GAT0 projections ----------------
// blob layout (147456 B): h0rz@0 | h0n@32768 | i1rz@49152 | i1n@81920 | h1rz@98304 | h1n@131072
__global__ __launch_bounds__(256) void k_preamble(const int* __restrict__ ei, int* __restrict__ counts,
                                                  const float* __restrict__ Wi0, const float* __restrict__ Wh0,
                                                  const float* __restrict__ Wi1, const float* __restrict__ Wh1,
                                                  float* __restrict__ WiT0, float* __restrict__ WhT0,
                                                  float* __restrict__ WiT1, float* __restrict__ WhT1,
                                                  float2* __restrict__ h0rz, float* __restrict__ h0n,
                                                  float2* __restrict__ i1rz, float* __restrict__ i1n,
                                                  float2* __restrict__ h1rz, float* __restrict__ h1n,
                                                  const float* __restrict__ x,     // [5N,16]
                                                  const float* __restrict__ W,    // [16,64]
                                                  const float* __restrict__ Wres, // [16,64]
                                                  const float* __restrict__ asrc, const float* __restrict__ adst,
                                                  float* __restrict__ xw, float* __restrict__ xres,
                                                  float* __restrict__ als, float* __restrict__ ald) {
    int b = blockIdx.x;
    if (b < CNT_BLKS) {
        int idx = b * 256 + threadIdx.x;
        if (idx >= ETOT) return;
        int dst = (idx < NEDGES) ? ei[NEDGES + idx] : (idx - NEDGES);
        atomicAdd(&counts[dst], 1);
        return;
    }
    if (b < CNT_BLKS + TRN_BLKS) {
        int idx = (b - CNT_BLKS) * 256 + threadIdx.x;
        if (idx < 6144)  { int k = idx / 192, r = idx % 192; WiT0[idx] = Wi0[r * 32 + k]; return; }
        idx -= 6144;
        if (idx < 12288) { int k = idx / 192, r = idx % 192; WhT0[idx] = Wh0[r * 64 + k]; return; }
        idx -= 12288;
        if (idx < 12288) { int k = idx / 192, r = idx % 192; WiT1[idx] = Wi1[r * 64 + k]; return; }
        idx -= 12288;
        if (idx < 12288) { int k = idx / 192, r = idx % 192; WhT1[idx] = Wh1[r * 64 + k]; return; }
        idx -= 12288;
        if (idx < 4096) { int k = idx >> 6, c = idx & 63;
                          h0rz[idx] = make_float2(Wh0[c * 64 + k], Wh0[(64 + c) * 64 + k]);
                          h0n[idx]  = Wh0[(128 + c) * 64 + k]; return; }
        idx -= 4096;
        if (idx < 4096) { int k = idx >> 6, c = idx & 63;
                          i1rz[idx] = make_float2(Wi1[c * 64 + k], Wi1[(64 + c) * 64 + k]);
                          i1n[idx]  = Wi1[(128 + c) * 64 + k]; return; }
        idx -= 4096;
        if (idx < 4096) { int k = idx >> 6, c = idx & 63;
                          h1rz[idx] = make_float2(Wh1[c * 64 + k], Wh1[(64 + c) * 64 + k]);
                          h1n[idx]  = Wh1[(128 + c) * 64 + k]; }
        return;
    }
    // ---- GAT0 projections (all timesteps) ----
    int wave = threadIdx.x >> 6, lane = threadIdx.x & 63;
    int m = (b - CNT_BLKS - TRN_BLKS) * 4 + wave;
    if (m >= NM) return;
    const float* xr = x + (size_t)m * F_IN;
    float xreg[F_IN];
#pragma unroll
    for (int k = 0; k < F_IN; k++) xreg[k] = xr[k];
    float acc = 0.f, accr = 0.f;
#pragma unroll
    for (int k = 0; k < F_IN; k++) {
        acc  += xreg[k] * W[k * 64 + lane];
        accr += xreg[k] * Wres[k * 64 + lane];
    }
    xw[(size_t)m * 64 + lane]   = acc;
    xres[(size_t)m * 64 + lane] = accr;
    float ps = acc * asrc[lane], pd = acc * adst[lane];
    for (int off = 16; off; off >>= 1) {
        ps += __shfl_down(ps, off, 32);
        pd += __shfl_down(pd, off, 32);
    }
    if ((lane & 31) == 0) {
        int h = lane >> 5;
        als[m * 2 + h] = ps;
        ald[m * 2 + h] = pd;
    }
}

// ---------------- fused GAT0 gather + ELU + residual + GAT1 projection, ALL timesteps ----------------
__global__ __launch_bounds__(256) void k_gat0_all(const float* __restrict__ xw,   // [5N,64]
                                                  const float* __restrict__ xres, // [5N,64]
                                                  const float* __restrict__ als,  // [5N,2]
                                                  const float* __restrict__ ald,  // [5N,2]
                                                  const int* __restrict__ offs, const int* __restrict__ csr,
                                                  const float* __restrict__ b,    // [64]
                                                  const float* __restrict__ W1,   // [64,32]
                                                  const float* __restrict__ Wres1,// [64,32]
                                                  const float* __restrict__ as1,  // [32]
                                                  const float* __restrict__ ad1v, // [32]
                                                  float* __restrict__ xw1, float* __restrict__ xres1,
                                                  float* __restrict__ als1, float* __restrict__ ald1) {
    int wave = threadIdx.x >> 6, lane = threadIdx.x & 63;
    int m = blockIdx.x * 4 + wave;
    if (m >= NM) return;
    int t = m / NNODES;
    int node = m - t * NNODES;
    int base = t * NNODES;
    int beg = offs[node], end = offs[node + 1];
    int deg = end - beg;
    float xresv = xres[(size_t)m * 64 + lane];          // early issue (used in epilogue)
    float ad0 = ald[m * 2 + 0], ad1 = ald[m * 2 + 1];
    float acc;
    if (deg <= 64) {
        int s = 0; float e0 = -INFINITY, e1 = -INFINITY;
        if (lane < deg) {
            s = base + csr[beg + lane];
            e0 = als[s * 2 + 0] + ad0; e0 = e0 > 0.f ? e0 : 0.2f * e0;
            e1 = als[s * 2 + 1] + ad1; e1 = e1 > 0.f ? e1 : 0.2f * e1;
        }
        float m0 = e0, m1 = e1;
        for (int o = 32; o; o >>= 1) {
            m0 = fmaxf(m0, __shfl_xor(m0, o));
            m1 = fmaxf(m1, __shfl_xor(m1, o));
        }
        float ex0 = (lane < deg) ? __expf(e0 - m0) : 0.f;
        float ex1 = (lane < deg) ? __expf(e1 - m1) : 0.f;
        float d0 = ex0, d1 = ex1;
        for (int o = 32; o; o >>= 1) {
            d0 += __shfl_xor(d0, o);
            d1 += __shfl_xor(d1, o);
        }
        ex0 *= 1.f / (d0 + 1e-16f);
        ex1 *= 1.f / (d1 + 1e-16f);
        // aggregation: 8 independent gathers in flight per iteration (all RL indices uniform)
        float a0 = 0.f, a1 = 0.f, a2 = 0.f, a3 = 0.f;
        int i = 0;
        for (; i + 8 <= deg; i += 8) {
            int   s0 = RLI(s, i),    s1 = RLI(s, i+1), s2 = RLI(s, i+2), s3 = RLI(s, i+3);
            int   s4 = RLI(s, i+4),  s5 = RLI(s, i+5), s6 = RLI(s, i+6), s7 = RLI(s, i+7);
            float x0 = xw[(size_t)s0 * 64 + lane];
            float x1 = xw[(size_t)s1 * 64 + lane];
            float x2 = xw[(size_t)s2 * 64 + lane];
            float x3 = xw[(size_t)s3 * 64 + lane];
            float x4 = xw[(size_t)s4 * 64 + lane];
            float x5 = xw[(size_t)s5 * 64 + lane];
            float x6 = xw[(size_t)s6 * 64 + lane];
            float x7 = xw[(size_t)s7 * 64 + lane];
            float u0 = (lane < 32) ? RL(ex0, i)   : RL(ex1, i);
            float u1 = (lane < 32) ? RL(ex0, i+1) : RL(ex1, i+1);
            float u2 = (lane < 32) ? RL(ex0, i+2) : RL(ex1, i+2);
            float u3 = (lane < 32) ? RL(ex0, i+3) : RL(ex1, i+3);
            float u4 = (lane < 32) ? RL(ex0, i+4) : RL(ex1, i+4);
            float u5 = (lane < 32) ? RL(ex0, i+5) : RL(ex1, i+5);
            float u6 = (lane < 32) ? RL(ex0, i+6) : RL(ex1, i+6);
            float u7 = (lane < 32) ? RL(ex0, i+7) : RL(ex1, i+7);
            a0 += u0 * x0 + u4 * x4;
            a1 += u1 * x1 + u5 * x5;
            a2 += u2 * x2 + u6 * x6;
            a3 += u3 * x3 + u7 * x7;
        }
        for (; i < deg; i++) {
            int s0 = RLI(s, i);
            float u = (lane < 32) ? RL(ex0, i) : RL(ex1, i);
            a0 += u * xw[(size_t)s0 * 64 + lane];
        }
        acc = (a0 + a1) + (a2 + a3);
    } else {
        float m0 = -INFINITY, m1 = -INFINITY;
        for (int i = beg + lane; i < end; i += 64) {
            int s = base + csr[i];
            float e0 = als[s * 2 + 0] + ad0; e0 = e0 > 0.f ? e0 : 0.2f * e0;
            float e1 = als[s * 2 + 1] + ad1; e1 = e1 > 0.f ? e1 : 0.2f * e1;
            m0 = fmaxf(m0, e0); m1 = fmaxf(m1, e1);
        }
        for (int o = 32; o; o >>= 1) {
            m0 = fmaxf(m0, __shfl_xor(m0, o));
            m1 = fmaxf(m1, __shfl_xor(m1, o));
        }
        float d0 = 0.f, d1 = 0.f;
        for (int i = beg + lane; i < end; i += 64) {
            int s = base + csr[i];
            float e0 = als[s * 2 + 0] + ad0; e0 = e0 > 0.f ? e0 : 0.2f * e0;
            float e1 = als[s * 2 + 1] + ad1; e1 = e1 > 0.f ? e1 : 0.2f * e1;
            d0 += __expf(e0 - m0); d1 += __expf(e1 - m1);
        }
        for (int o = 32; o; o >>= 1) { d0 += __shfl_xor(d0, o); d1 += __shfl_xor(d1, o); }
        float inv0 = 1.f / (d0 + 1e-16f), inv1 = 1.f / (d1 + 1e-16f);
        acc = 0.f;
        for (int i = beg; i < end; i++) {
            int s = base + csr[i];
            float e, wgt;
            if (lane < 32) { e = als[s * 2 + 0] + ad0; e = e > 0.f ? e : 0.2f * e; wgt = __expf(e - m0) * inv0; }
            else           { e = als[s * 2 + 1] + ad1; e = e > 0.f ? e : 0.2f * e; wgt = __expf(e - m1) * inv1; }
            acc += wgt * xw[(size_t)s * 64 + lane];
        }
    }
    float x1v = acc + b[lane];
    x1v = x1v > 0.f ? x1v : expm1f(x1v);
    x1v += xresv;
    // GAT1 projection: readlane broadcasts
    int j = lane & 31;
    const float* Wp = (lane < 32) ? W1 : Wres1;
    float pacc = 0.f;
#pragma unroll
    for (int k = 0; k < 64; k++) {
        float xv = RL(x1v, k);
        pacc += xv * Wp[k * 32 + j];
    }
    if (lane < 32) xw1[(size_t)m * 32 + j]   = pacc;
    else           xres1[(size_t)m * 32 + j] = pacc;
    float ps = (lane < 32) ? pacc * as1[j]  : 0.f;
    float pd = (lane < 32) ? pacc * ad1v[j] : 0.f;
    for (int o = 16; o; o >>= 1) {
        ps += __shfl_down(ps, o, 32);
        pd += __shfl_down(pd, o, 32);
    }
    if (lane == 0) { als1[m] = ps; ald1[m] = pd; }
}

// ---------------- GAT1 gather -> x2 -> fused GRU0 input projection gi0, ALL timesteps ----------------
__global__ __launch_bounds__(256) void k_gat1_all(const float* __restrict__ xw1,   // [5N,32]
                                                  const float* __restrict__ xres1, // [5N,32]
                                                  const float* __restrict__ als1,  // [5N]
                                                  const float* __restrict__ ald1,  // [5N]
                                                  const int* __restrict__ offs, const int* __restrict__ csr,
                                                  const float* __restrict__ b,     // [32]
                                                  const float* __restrict__ WiT0,  // [32,192] k-major
                                                  const float* __restrict__ bi0,   // [192]
                                                  float* __restrict__ gi0) {
    int wave = threadIdx.x >> 6, lane = threadIdx.x & 63;
    int m = blockIdx.x * 4 + wave;
    if (m >= NM) return;
    int t = m / NNODES;
    int node = m - t * NNODES;
    int base = t * NNODES;
    int beg = offs[node], end = offs[node + 1];
    int deg = end - beg;
    int ch = lane & 31, half = lane >> 5;
    float xres1v = xres1[(size_t)m * 32 + ch];          // early issue
    float adv = ald1[m];
    float aggr;
    if (deg <= 64) {
        int s = 0; float e = -INFINITY;
        if (lane < deg) {
            s = base + csr[beg + lane];
            e = als1[s] + adv; e = e > 0.f ? e : 0.2f * e;
        }
        float mx = e;
        for (int o = 32; o; o >>= 1) mx = fmaxf(mx, __shfl_xor(mx, o));
        float ex = (lane < deg) ? __expf(e - mx) : 0.f;
        float d = ex;
        for (int o = 32; o; o >>= 1) d += __shfl_xor(d, o);
        ex *= 1.f / (d + 1e-16f);
        // 8 edges per iteration: uniform readlanes for all 8, per-half SELECT (legal)
        float acc0 = 0.f, acc1 = 0.f;
        int i = 0;
        for (; i + 8 <= deg; i += 8) {
            int   e0 = RLI(s, i),   o0 = RLI(s, i+1);
            int   e1 = RLI(s, i+2), o1 = RLI(s, i+3);
            int   e2 = RLI(s, i+4), o2 = RLI(s, i+5);
            int   e3 = RLI(s, i+6), o3 = RLI(s, i+7);
            int   sa0 = half ? o0 : e0, sa1 = half ? o1 : e1;
            int   sa2 = half ? o2 : e2, sa3 = half ? o3 : e3;
            float xa0 = xw1[(size_t)sa0 * 32 + ch];
            float xa1 = xw1[(size_t)sa1 * 32 + ch];
            float xa2 = xw1[(size_t)sa2 * 32 + ch];
            float xa3 = xw1[(size_t)sa3 * 32 + ch];
            float we0 = RL(ex, i),   wo0 = RL(ex, i+1);
            float we1 = RL(ex, i+2), wo1 = RL(ex, i+3);
            float we2 = RL(ex, i+4), wo2 = RL(ex, i+5);
            float we3 = RL(ex, i+6), wo3 = RL(ex, i+7);
            float wa0 = half ? wo0 : we0, wa1 = half ? wo1 : we1;
            float wa2 = half ? wo2 : we2, wa3 = half ? wo3 : we3;
            acc0 += wa0 * xa0 + wa2 * xa2;
            acc1 += wa1 * xa1 + wa3 * xa3;
        }
        for (; i < deg; i += 2) {
            int i2 = (i + 1 < deg) ? i + 1 : i;
            int   sa = RLI(s, i),  sb = RLI(s, i2);
            float wa = RL(ex, i),  wb = RL(ex, i2);
            if (i + 1 >= deg) wb = 0.f;
            int   sm = half ? sb : sa;
            float wm = half ? wb : wa;
            acc0 += wm * xw1[(size_t)sm * 32 + ch];
        }
        float acc = acc0 + acc1;
        acc += __shfl_xor(acc, 32);
        aggr = acc;
    } else {
        float mx = -INFINITY;
        for (int i = beg + lane; i < end; i += 64) {
            float e = als1[base + csr[i]] + adv; e = e > 0.f ? e : 0.2f * e;
            mx = fmaxf(mx, e);
        }
        for (int o = 32; o; o >>= 1) mx = fmaxf(mx, __shfl_xor(mx, o));
        float d = 0.f;
        for (int i = beg + lane; i < end; i += 64) {
            float e = als1[base + csr[i]] + adv; e = e > 0.f ? e : 0.2f * e;
            d += __expf(e - mx);
        }
        for (int o = 32; o; o >>= 1) d += __shfl_xor(d, o);
        float inv = 1.f / (d + 1e-16f);
        float acc = 0.f;
        for (int i = beg; i < end; i++) {
            int s = base + csr[i];
            float e = als1[s] + adv; e = e > 0.f ? e : 0.2f * e;
            float wgt = __expf(e - mx) * inv;
            acc += wgt * xw1[(size_t)s * 32 + ch];
        }
        aggr = acc;
    }
    // x2 value (identical on both wave halves: ch = lane&31)
    float v = aggr + b[ch];
    v = v > 0.f ? v : expm1f(v);
    float x2v = v + xres1v;
    // gi0 = x2 @ WiT0 + bi0 — k-outer: one RL serves three output blocks (32 RLs not 96)
    float p0 = bi0[lane], p1 = bi0[64 + lane], p2 = bi0[128 + lane];
#pragma unroll 8
    for (int k = 0; k < 32; k++) {
        float xv = RL(x2v, k);
        p0 += xv * WiT0[k * 192 + lane];
        p1 += xv * WiT0[k * 192 + 64 + lane];
        p2 += xv * WiT0[k * 192 + 128 + lane];
    }
    gi0[(size_t)m * 192 + lane]       = p0;
    gi0[(size_t)m * 192 + 64 + lane]  = p1;
    gi0[(size_t)m * 192 + 128 + lane] = p2;
}

// ---------------- persistent-LDS GRU chain + head: RL broadcasts, 2 DS/k, gi0 software pipeline ----------------
__global__ __launch_bounds__(512) void k_gruhead_p(const float* __restrict__ gi0,    // [5N,192]
                                                   const float4* __restrict__ wblob, // packed weights, 147456 B
                                                   const float* __restrict__ bh0,
                                                   const float* __restrict__ bi1, const float* __restrict__ bh1,
                                                   const float* __restrict__ fc1W, const float* __restrict__ fc1b,
                                                   const float* __restrict__ fc2W, const float* __restrict__ fc2b,
                                                   float* __restrict__ out) {
    extern __shared__ char ldsraw[];                // 147456 B
    float2* Lh0rz = (float2*)ldsraw;                // 32768
    float*  Lh0n  = (float*)(ldsraw + 32768);       // 16384
    float2* Li1rz = (float2*)(ldsraw + 49152);
    float*  Li1n  = (float*)(ldsraw + 81920);
    float2* Lh1rz = (float2*)(ldsraw + 98304);
    float*  Lh1n  = (float*)(ldsraw + 131072);
    int tid = threadIdx.x, wave = tid >> 6, lane = tid & 63;
    int node0 = (blockIdx.x * GW + wave) * GNPW;    // 250*8*5 = 10000 exactly

    {
        float4* D = (float4*)ldsraw;
#pragma unroll
        for (int i = 0; i < 18; i++) D[tid + i * 512] = wblob[tid + i * 512];
    }

    // prefetch t=0 gi0 while LDS staging drains
    float pr[GNPW], pz[GNPW], pn[GNPW];
#pragma unroll
    for (int n = 0; n < GNPW; n++) {
        size_t gb = ((size_t)node0 + n) * 192;
        pr[n] = gi0[gb + lane];
        pz[n] = gi0[gb + 64 + lane];
        pn[n] = gi0[gb + 128 + lane];
    }
    __syncthreads();                                // the only barrier

    float bhr0 = bh0[lane], bhz0 = bh0[64 + lane], bhn0 = bh0[128 + lane];
    float bir1 = bi1[lane] + bh1[lane];
    float biz1 = bi1[64 + lane] + bh1[64 + lane];
    float bin1 = bi1[128 + lane], bhn1 = bh1[128 + lane];

    float h0[GNPW] = {0.f, 0.f, 0.f, 0.f, 0.f};
    float h1[GNPW] = {0.f, 0.f, 0.f, 0.f, 0.f};

    for (int t = 0; t < T_STEPS; t++) {
        float gr[GNPW], gz[GNPW], gin[GNPW], ghn[GNPW];
#pragma unroll
        for (int n = 0; n < GNPW; n++) {
            gr[n]  = pr[n] + bhr0;
            gz[n]  = pz[n] + bhz0;
            gin[n] = pn[n];
            ghn[n] = bhn0;
        }
        // issue prefetch for t+1 now — hidden under the k-loops below
        if (t + 1 < T_STEPS) {
            size_t gb1 = ((size_t)(t + 1) * NNODES + node0) * 192;
#pragma unroll
            for (int n = 0; n < GNPW; n++) {
                pr[n] = gi0[gb1 + n * 192 + lane];
                pz[n] = gi0[gb1 + n * 192 + 64 + lane];
                pn[n] = gi0[gb1 + n * 192 + 128 + lane];
            }
        }
        // GRU0 h-part (K=64): 2 DS reads per k
#pragma unroll 8
        for (int k = 0; k < 64; k++) {
            float2 wrz = Lh0rz[k * 64 + lane];
            float  wn  = Lh0n[k * 64 + lane];
#pragma unroll
            for (int n = 0; n < GNPW; n++) {
                float hv = RL(h0[n], k);
                gr[n] += hv * wrz.x; gz[n] += hv * wrz.y; ghn[n] += hv * wn;
            }
        }
#pragma unroll
        for (int n = 0; n < GNPW; n++) {
            float r = 1.f / (1.f + __expf(-gr[n]));
            float z = 1.f / (1.f + __expf(-gz[n]));
            float nn = tanhf(gin[n] + r * ghn[n]);
            h0[n] = (1.f - z) * nn + z * h0[n];
        }

        // GRU1 x-pass (x = h0 new)
#pragma unroll
        for (int n = 0; n < GNPW; n++) { gr[n] = bir1; gz[n] = biz1; gin[n] = bin1; }
#pragma unroll 8
        for (int k = 0; k < 64; k++) {
            float2 wrz = Li1rz[k * 64 + lane];
            float  wn  = Li1n[k * 64 + lane];
#pragma unroll
            for (int n = 0; n < GNPW; n++) {
                float xv = RL(h0[n], k);
                gr[n] += xv * wrz.x; gz[n] += xv * wrz.y; gin[n] += xv * wn;
            }
        }
        // GRU1 h-pass
#pragma unroll
        for (int n = 0; n < GNPW; n++) ghn[n] = bhn1;
#pragma unroll 8
        for (int k = 0; k < 64; k++) {
            float2 wrz = Lh1rz[k * 64 + lane];
            float  wn  = Lh1n[k * 64 + lane];
#pragma unroll
            for (int n = 0; n < GNPW; n++) {
                float hv = RL(h1[n], k);
                gr[n] += hv * wrz.x; gz[n] += hv * wrz.y; ghn[n] += hv * wn;
            }
        }
#pragma unroll
        for (int n = 0; n < GNPW; n++) {
            float r = 1.f / (1.f + __expf(-gr[n]));
            float z = 1.f / (1.f + __expf(-gz[n]));
            float nn = tanhf(gin[n] + r * ghn[n]);
            h1[n] = (1.f - z) * nn + z * h1[n];
        }
    }

    // MLP head
    int j = lane & 31, half = lane >> 5;
#pragma unroll
    for (int p = 0; p < 3; p++) {
        int ne = 2 * p;
        int no = (2 * p + 1 < GNPW) ? 2 * p + 1 : 2 * p;
        float a = fc1b[j];
#pragma unroll
        for (int k = 0; k < 64; k++) {
            float he = RL(h1[ne], k);
            float ho = RL(h1[no], k);
            a += (half ? ho : he) * fc1W[k * 32 + j];
        }
        a = fmaxf(a, 0.f);
        float v = a * fc2W[j];
        for (int o = 16; o; o >>= 1) v += __shfl_down(v, o, 32);
        if ((lane & 31) == 0 && 2 * p + half < GNPW) out[node0 + 2 * p + half] = v + fc2b[0];
    }
}

// ---------------- fallback: per-phase LDS staging (49KB static), flat weights ----------------
__global__ __launch_bounds__(512) void k_gruhead(const float* __restrict__ gi0,
                                                 const float* __restrict__ WhT0,
                                                 const float* __restrict__ WiT1,
                                                 const float* __restrict__ WhT1,
                                                 const float* __restrict__ bh0,
                                                 const float* __restrict__ bi1, const float* __restrict__ bh1,
                                                 const float* __restrict__ fc1W, const float* __restrict__ fc1b,
                                                 const float* __restrict__ fc2W, const float* __restrict__ fc2b,
                                                 float* __restrict__ out) {
    __shared__ float lw[64 * 192];
    int tid = threadIdx.x;
    int wave = tid >> 6, lane = tid & 63;
    int node0 = (blockIdx.x * GW + wave) * GNPW;

    float bhr0 = bh0[lane], bhz0 = bh0[64 + lane], bhn0 = bh0[128 + lane];
    float bir1 = bi1[lane] + bh1[lane];
    float biz1 = bi1[64 + lane] + bh1[64 + lane];
    float bin1 = bi1[128 + lane], bhn1 = bh1[128 + lane];

    float h0[GNPW] = {0.f, 0.f, 0.f, 0.f, 0.f};
    float h1[GNPW] = {0.f, 0.f, 0.f, 0.f, 0.f};

    auto stage = [&](const float* __restrict__ src) {
        __syncthreads();
        const float4* s4 = (const float4*)src;
        float4* d4 = (float4*)lw;
#pragma unroll
        for (int i = 0; i < 6; i++) d4[tid + i * 512] = s4[tid + i * 512];
        __syncthreads();
    };

    for (int t = 0; t < T_STEPS; t++) {
        float gr[GNPW], gz[GNPW], gin[GNPW], ghn[GNPW];
        size_t gb = ((size_t)t * NNODES + node0) * 192;
#pragma unroll
        for (int n = 0; n < GNPW; n++) {
            gr[n]  = gi0[gb + n * 192 + lane] + bhr0;
            gz[n]  = gi0[gb + n * 192 + 64 + lane] + bhz0;
            gin[n] = gi0[gb + n * 192 + 128 + lane];
            ghn[n] = bhn0;
        }
        stage(WhT0);
#pragma unroll 4
        for (int k = 0; k < 64; k++) {
            float wr = lw[k * 192 + lane];
            float wz = lw[k * 192 + 64 + lane];
            float wn = lw[k * 192 + 128 + lane];
#pragma unroll
            for (int n = 0; n < GNPW; n++) {
                float hv = RL(h0[n], k);
                gr[n] += hv * wr; gz[n] += hv * wz; ghn[n] += hv * wn;
            }
        }
#pragma unroll
        for (int n = 0; n < GNPW; n++) {
            float r = 1.f / (1.f + __expf(-gr[n]));
            float z = 1.f / (1.f + __expf(-gz[n]));
            float nn = tanhf(gin[n] + r * ghn[n]);
            h0[n] = (1.f - z) * nn + z * h0[n];
        }
#pragma unroll
        for (int n = 0; n < GNPW; n++) { gr[n] = bir1; gz[n] = biz1; gin[n] = bin1; }
        stage(WiT1);
#pragma unroll 4
        for (int k = 0; k < 64; k++) {
            float wir = lw[k * 192 + lane];
            float wiz = lw[k * 192 + 64 + lane];
            float win = lw[k * 192 + 128 + lane];
#pragma unroll
            for (int n = 0; n < GNPW; n++) {
                float xv = RL(h0[n], k);
                gr[n] += xv * wir; gz[n] += xv * wiz; gin[n] += xv * win;
            }
        }
#pragma unroll
        for (int n = 0; n < GNPW; n++) ghn[n] = bhn1;
        stage(WhT1);
#pragma unroll 4
        for (int k = 0; k < 64; k++) {
            float whr = lw[k * 192 + lane];
            float whz = lw[k * 192 + 64 + lane];
            float whn = lw[k * 192 + 128 + lane];
#pragma unroll
            for (int n = 0; n < GNPW; n++) {
                float hv = RL(h1[n], k);
                gr[n] += hv * whr; gz[n] += hv * whz; ghn[n] += hv * whn;
            }
        }
#pragma unroll
        for (int n = 0; n < GNPW; n++) {
            float r = 1.f / (1.f + __expf(-gr[n]));
            float z = 1.f / (1.f + __expf(-gz[n]));
            float nn = tanhf(gin[n] + r * ghn[n]);
            h1[n] = (1.f - z) * nn + z * h1[n];
        }
    }

    int j = lane & 31, half = lane >> 5;
#pragma unroll
    for (int p = 0; p < 3; p++) {
        int ne = 2 * p;
        int no = (2 * p + 1 < GNPW) ? 2 * p + 1 : 2 * p;
        float a = fc1b[j];
#pragma unroll
        for (int k = 0; k < 64; k++) {
            float he = RL(h1[ne], k);
            float ho = RL(h1[no], k);
            a += (half ? ho : he) * fc1W[k * 32 + j];
        }
        a = fmaxf(a, 0.f);
        float v = a * fc2W[j];
        for (int o = 16; o; o >>= 1) v += __shfl_down(v, o, 32);
        if ((lane & 31) == 0 && 2 * p + half < GNPW) out[node0 + 2 * p + half] = v + fc2b[0];
    }
}

extern "C" void kernel_launch(void* const* d_in, const int* in_sizes, int n_in,
                              void* d_out, int out_size, void* d_ws, size_t ws_size,
                              hipStream_t stream) {
    const float* x_seq   = (const float*)d_in[0];
    const int*   ei      = (const int*)d_in[1];
    const float* gat0_W  = (const float*)d_in[2];
    const float* gat0_as = (const float*)d_in[3];
    const float* gat0_ad = (const float*)d_in[4];
    const float* gat0_b  = (const float*)d_in[5];
    const float* res0_W  = (const float*)d_in[6];
    const float* gat1_W  = (const float*)d_in[7];
    const float* gat1_as = (const float*)d_in[8];
    const float* gat1_ad = (const float*)d_in[9];
    const float* gat1_b  = (const float*)d_in[10];
    const float* res1_W  = (const float*)d_in[11];
    const float* gru0_Wi = (const float*)d_in[12];
    const float* gru0_Wh = (const float*)d_in[13];
    const float* gru0_bi = (const float*)d_in[14];
    const float* gru0_bh = (const float*)d_in[15];
    const float* gru1_Wi = (const float*)d_in[16];
    const float* gru1_Wh = (const float*)d_in[17];
    const float* gru1_bi = (const float*)d_in[18];
    const float* gru1_bh = (const float*)d_in[19];
    const float* fc1_W   = (const float*)d_in[20];
    const float* fc1_b   = (const float*)d_in[21];
    const float* fc2_W   = (const float*)d_in[22];
    const float* fc2_b   = (const float*)d_in[23];
    float* out = (float*)d_out;

    char* w = (char*)d_ws;
    size_t off = 0;
    auto take = [&](size_t bytes) { size_t r = off; off += (bytes + 255) & ~(size_t)255; return r; };
    const size_t N = NNODES, M = NM;
    int*   counts = (int*)(w + take(N * 4));
    int*   cursor = (int*)(w + take(N * 4));
    size_t zero_span = off;                              // counts+cursor contiguous
    int*   offs   = (int*)(w + take((N + 1) * 4));
    int*   csr    = (int*)(w + take((size_t)ETOT * 4));
    float* xw0    = (float*)(w + take(M * 64 * 4));
    float* xres0  = (float*)(w + take(M * 64 * 4));
    float* als0   = (float*)(w + take(M * 2 * 4));
    float* ald0   = (float*)(w + take(M * 2 * 4));
    float* xw1    = (float*)(w + take(M * 32 * 4));
    float* xres1  = (float*)(w + take(M * 32 * 4));
    float* als1   = (float*)(w + take(M * 4));
    float* ald1   = (float*)(w + take(M * 4));
    float* gi0    = (float*)(w + take(M * 192 * 4));   // 38.4 MB
    float* wiT0   = (float*)(w + take(32 * 192 * 4));
    float* whT0   = (float*)(w + take(64 * 192 * 4));
    float* wiT1   = (float*)(w + take(64 * 192 * 4));
    float* whT1   = (float*)(w + take(64 * 192 * 4));
    // packed blob: h0rz|h0n|i1rz|i1n|h1rz|h1n contiguous (147456 B)
    char*   blob  = w + take(147456);
    float2* h0rz  = (float2*)blob;
    float*  h0n   = (float*)(blob + 32768);
    float2* i1rz  = (float2*)(blob + 49152);
    float*  i1n   = (float*)(blob + 81920);
    float2* h1rz  = (float2*)(blob + 98304);
    float*  h1n   = (float*)(blob + 131072);

    hipMemsetAsync(w, 0, zero_span, stream);            // counts + cursor in one memset

    // fused preamble: edge count | weight transpose | GAT0 projections (independent partitions)
    k_preamble<<<CNT_BLKS + TRN_BLKS + MM0_BLKS, 256, 0, stream>>>(
        ei, counts,
        gru0_Wi, gru0_Wh, gru1_Wi, gru1_Wh,
        wiT0, whT0, wiT1, whT1,
        h0rz, h0n, i1rz, i1n, h1rz, h1n,
        x_seq, gat0_W, res0_W, gat0_as, gat0_ad, xw0, xres0, als0, ald0);

    k_scan<<<1, 1024, 0, stream>>>(counts, offs);
    k_fill<<<CNT_BLKS, 256, 0, stream>>>(ei, offs, cursor, csr);

    k_gat0_all<<<MM0_BLKS, 256, 0, stream>>>(xw0, xres0, als0, ald0, offs, csr, gat0_b,
                                             gat1_W, res1_W, gat1_as, gat1_ad,
                                             xw1, xres1, als1, ald1);
    k_gat1_all<<<MM0_BLKS, 256, 0, stream>>>(xw1, xres1, als1, ald1, offs, csr, gat1_b,
                                             wiT0, gru0_bi, gi0);

    // Recurrent chain + head: persistent-LDS variant (147456 B dyn shared)
    const int ggrid = NNODES / (GW * GNPW);   // 250
    hipError_t ae = hipFuncSetAttribute(reinterpret_cast<const void*>(k_gruhead_p),
                                        hipFuncAttributeMaxDynamicSharedMemorySize, 147456);
    if (ae == hipSuccess) {
        k_gruhead_p<<<ggrid, 512, 147456, stream>>>(gi0, (const float4*)blob,
                                                    gru0_bh, gru1_bi, gru1_bh,
                                                    fc1_W, fc1_b, fc2_W, fc2_b, out);
    } else {
        k_gruhead<<<ggrid, 512, 0, stream>>>(gi0, whT0, wiT1, whT1,
                                             gru0_bh, gru1_bi, gru1_bh,
                                             fc1_W, fc1_b, fc2_W, fc2_b, out);
    }
}